// Round 1
// baseline (1289.873 us; speedup 1.0000x reference)
//
#include <hip/hip_runtime.h>
#include <math.h>

// Problem dims
#define S_ 512
#define HID_ 768
#define H_ 12
#define D_ 64
#define FF_ 3072

typedef float f32x4 __attribute__((ext_vector_type(4)));
typedef short bf16x8 __attribute__((ext_vector_type(8)));

__device__ __forceinline__ unsigned short f2bf(float x) {
  union { float f; unsigned int u; } v; v.f = x;
  unsigned int r = v.u + 0x7FFFu + ((v.u >> 16) & 1u);
  return (unsigned short)(r >> 16);
}
__device__ __forceinline__ float bf2f(unsigned short s) {
  union { float f; unsigned int u; } v; v.u = ((unsigned int)s) << 16;
  return v.f;
}

// ---------------------------------------------------------------------------
// Generic MFMA GEMM, C = alpha * A@B (+bias (+res | gelu)), bf16x3 split for
// near-f32 accuracy. A: M x K row-major (lda). B: NN -> K x N row-major (ldb);
// NT -> N x K row-major (ldb). Batched via blockIdx.z with (b,h) strides.
// EPI: 0 = store, 1 = +bias, 2 = +bias +res, 3 = +bias then gelu.
// ---------------------------------------------------------------------------
template<bool NT, int EPI>
__global__ __launch_bounds__(256)
void gemm_kernel(const float* __restrict__ Ag, const float* __restrict__ Bg,
                 const float* __restrict__ bias, const float* __restrict__ resg,
                 float* __restrict__ Cg,
                 int M, int N, int K, int lda, int ldb, int ldc,
                 long sAb, long sAh, long sBb, long sBh, long sCb, long sCh,
                 int Hd, float alpha)
{
  __shared__ unsigned short Ahs[128][40];
  __shared__ unsigned short Als[128][40];
  __shared__ unsigned short Bhs[128][40];
  __shared__ unsigned short Bls[128][40];

  const int z  = blockIdx.z;
  const int zb = z / Hd, zh = z - zb * Hd;
  const float* A  = Ag + zb * sAb + zh * sAh;
  const float* Bp = Bg + zb * sBb + zh * sBh;
  float* C = Cg + zb * sCb + zh * sCh;
  const float* R = resg ? (resg + zb * sCb + zh * sCh) : nullptr;

  const int tid = threadIdx.x;
  const int m0 = blockIdx.x * 128, n0 = blockIdx.y * 128;
  const int lane = tid & 63;
  const int wid = tid >> 6;
  const int wm = (wid >> 1) * 64, wn = (wid & 1) * 64;
  const int l15 = lane & 15, lk = (lane >> 4) * 8;

  f32x4 acc[4][4] = {};

  for (int k0 = 0; k0 < K; k0 += 32) {
    __syncthreads();
    // ---- stage A (128 x 32), f32 -> bf16 hi/lo
#pragma unroll
    for (int p = 0; p < 4; ++p) {
      const int f4 = p * 256 + tid;
      const int row = f4 >> 3, c4 = (f4 & 7) << 2;
      float x0 = 0.f, x1 = 0.f, x2 = 0.f, x3 = 0.f;
      if (m0 + row < M) {
        const float4 v = *reinterpret_cast<const float4*>(A + (long)(m0 + row) * lda + k0 + c4);
        x0 = v.x; x1 = v.y; x2 = v.z; x3 = v.w;
      }
      ushort4 hh, ll;
      hh.x = f2bf(x0); ll.x = f2bf(x0 - bf2f(hh.x));
      hh.y = f2bf(x1); ll.y = f2bf(x1 - bf2f(hh.y));
      hh.z = f2bf(x2); ll.z = f2bf(x2 - bf2f(hh.z));
      hh.w = f2bf(x3); ll.w = f2bf(x3 - bf2f(hh.w));
      *reinterpret_cast<ushort4*>(&Ahs[row][c4]) = hh;
      *reinterpret_cast<ushort4*>(&Als[row][c4]) = ll;
    }
    // ---- stage B into [n][k] layout
    if (NT) {
#pragma unroll
      for (int p = 0; p < 4; ++p) {
        const int f4 = p * 256 + tid;
        const int row = f4 >> 3, c4 = (f4 & 7) << 2;
        float x0 = 0.f, x1 = 0.f, x2 = 0.f, x3 = 0.f;
        if (n0 + row < N) {
          const float4 v = *reinterpret_cast<const float4*>(Bp + (long)(n0 + row) * ldb + k0 + c4);
          x0 = v.x; x1 = v.y; x2 = v.z; x3 = v.w;
        }
        ushort4 hh, ll;
        hh.x = f2bf(x0); ll.x = f2bf(x0 - bf2f(hh.x));
        hh.y = f2bf(x1); ll.y = f2bf(x1 - bf2f(hh.y));
        hh.z = f2bf(x2); ll.z = f2bf(x2 - bf2f(hh.z));
        hh.w = f2bf(x3); ll.w = f2bf(x3 - bf2f(hh.w));
        *reinterpret_cast<ushort4*>(&Bhs[row][c4]) = hh;
        *reinterpret_cast<ushort4*>(&Bls[row][c4]) = ll;
      }
    } else {
#pragma unroll
      for (int p = 0; p < 4; ++p) {
        const int f4 = p * 256 + tid;
        const int kr = f4 >> 5, n4 = (f4 & 31) << 2;
        float x[4] = {0.f, 0.f, 0.f, 0.f};
        if (n0 + n4 < N) {
          const float4 v = *reinterpret_cast<const float4*>(Bp + (long)(k0 + kr) * ldb + n0 + n4);
          x[0] = v.x; x[1] = v.y; x[2] = v.z; x[3] = v.w;
        }
#pragma unroll
        for (int e = 0; e < 4; ++e) {
          const unsigned short hh = f2bf(x[e]);
          Bhs[n4 + e][kr] = hh;
          Bls[n4 + e][kr] = f2bf(x[e] - bf2f(hh));
        }
      }
    }
    __syncthreads();

    // ---- fragments + MFMA (bf16x3: hh + hl + lh)
    bf16x8 a_h[4], a_l[4], b_h[4], b_l[4];
#pragma unroll
    for (int t = 0; t < 4; ++t) {
      a_h[t] = *reinterpret_cast<const bf16x8*>(&Ahs[wm + t * 16 + l15][lk]);
      a_l[t] = *reinterpret_cast<const bf16x8*>(&Als[wm + t * 16 + l15][lk]);
      b_h[t] = *reinterpret_cast<const bf16x8*>(&Bhs[wn + t * 16 + l15][lk]);
      b_l[t] = *reinterpret_cast<const bf16x8*>(&Bls[wn + t * 16 + l15][lk]);
    }
#pragma unroll
    for (int i = 0; i < 4; ++i)
#pragma unroll
      for (int j = 0; j < 4; ++j) {
        acc[i][j] = __builtin_amdgcn_mfma_f32_16x16x32_bf16(a_h[i], b_h[j], acc[i][j], 0, 0, 0);
        acc[i][j] = __builtin_amdgcn_mfma_f32_16x16x32_bf16(a_h[i], b_l[j], acc[i][j], 0, 0, 0);
        acc[i][j] = __builtin_amdgcn_mfma_f32_16x16x32_bf16(a_l[i], b_h[j], acc[i][j], 0, 0, 0);
      }
  }

  // ---- epilogue: D row = (lane>>4)*4 + r, col = lane&15 (verified mapping)
#pragma unroll
  for (int i = 0; i < 4; ++i) {
    const int rbase = m0 + wm + i * 16 + ((lane >> 4) << 2);
#pragma unroll
    for (int j = 0; j < 4; ++j) {
      const int col = n0 + wn + j * 16 + l15;
      if (col >= N) continue;
#pragma unroll
      for (int r = 0; r < 4; ++r) {
        const int row = rbase + r;
        if (row >= M) continue;
        float v = acc[i][j][r] * alpha;
        if (EPI >= 1) v += bias[col];
        const long idx = (long)row * ldc + col;
        if (EPI == 2) v += R[idx];
        if (EPI == 3) v = 0.5f * v * (1.0f + erff(v * 0.70710678118654752440f));
        C[idx] = v;
      }
    }
  }
}

// ---------------------------------------------------------------------------
// qr[b,i,h,r] = sum_d q[b,i,h*64+d] * Wr[r*64+d];  qbr[b,i,h] = sum_d q*br[d]
// ---------------------------------------------------------------------------
__global__ __launch_bounds__(256)
void qr_kernel(const float* __restrict__ q, const float* __restrict__ Wr,
               const float* __restrict__ br, float* __restrict__ qr,
               float* __restrict__ qbr)
{
  __shared__ float qrow[768];
  __shared__ float wr[64][65];
  __shared__ float brs[64];
  const long bi = blockIdx.x;
  const int tid = threadIdx.x;
  for (int t = tid; t < 768; t += 256) qrow[t] = q[bi * 768 + t];
  for (int t = tid; t < 4096; t += 256) wr[t >> 6][t & 63] = Wr[t];
  if (tid < 64) brs[tid] = br[tid];
  __syncthreads();
  for (int o = tid; o < 768; o += 256) {
    const int h = o >> 6, r = o & 63;
    float s = 0.f;
#pragma unroll 8
    for (int d = 0; d < 64; ++d) s += qrow[h * 64 + d] * wr[r][d];
    qr[bi * 768 + o] = s;
  }
  if (tid < 12) {
    float s = 0.f;
#pragma unroll 8
    for (int d = 0; d < 64; ++d) s += qrow[tid * 64 + d] * brs[d];
    qbr[bi * 12 + tid] = s;
  }
}

// ---------------------------------------------------------------------------
// Per (b,i): s[h][j] = qk_scaled + (qr.rel + qbr)/8 + (1-g)*NEG; softmax over j
// Streams rel[b,i,:,:] exactly once. In-place scores -> probs.
// ---------------------------------------------------------------------------
__global__ __launch_bounds__(256)
void relsm_kernel(const float* __restrict__ rel, const float* __restrict__ graph,
                  const float* __restrict__ qr, const float* __restrict__ qbr,
                  float* __restrict__ sc)
{
  __shared__ float s[12][512];
  __shared__ float qrl[12][65];
  __shared__ float rt[64][65];
  __shared__ float gl[512];
  __shared__ float qb[12];
  const int bi = blockIdx.x;
  const int b = bi >> 9, i = bi & 511;
  const int tid = threadIdx.x;

  for (int t = tid; t < 768; t += 256) qrl[t >> 6][t & 63] = qr[(long)bi * 768 + t];
  if (tid < 12) qb[tid] = qbr[(long)bi * 12 + tid];
  for (int t = tid; t < 512; t += 256) gl[t] = graph[(long)bi * 512 + t];
  for (int t = tid; t < 6144; t += 256) {
    const int h = t >> 9, j = t & 511;
    s[h][j] = sc[(((long)(b * 12 + h) * 512) + i) * 512 + j];
  }

  for (int jt = 0; jt < 512; jt += 64) {
    __syncthreads();
    const float* rb = rel + ((long)bi * 512 + jt) * 64;
#pragma unroll
    for (int p = 0; p < 4; ++p) {
      const int f4 = p * 256 + tid;
      const int r_ = f4 >> 4, c4 = (f4 & 15) << 2;
      const float4 v = *reinterpret_cast<const float4*>(rb + r_ * 64 + c4);
      rt[r_][c4] = v.x; rt[r_][c4 + 1] = v.y; rt[r_][c4 + 2] = v.z; rt[r_][c4 + 3] = v.w;
    }
    __syncthreads();
#pragma unroll
    for (int p = 0; p < 3; ++p) {
      const int o = p * 256 + tid;       // 768 = 64 j x 12 h
      const int jl = o / 12, h = o - jl * 12;
      float dot = 0.f;
#pragma unroll 8
      for (int r = 0; r < 64; ++r) dot += qrl[h][r] * rt[jl][r];
      s[h][jt + jl] += dot * 0.125f;
    }
  }
  __syncthreads();

  const int wv = tid >> 6, ln = tid & 63;
  for (int h = wv; h < 12; h += 4) {
    const float qb8 = qb[h] * 0.125f;
    float vals[8];
    float mx = -3.4e38f;
#pragma unroll
    for (int t = 0; t < 8; ++t) {
      const int j = ln + (t << 6);
      const float x = s[h][j] + qb8 + (1.0f - gl[j]) * (-1.0e9f);
      vals[t] = x;
      mx = fmaxf(mx, x);
    }
#pragma unroll
    for (int off = 32; off > 0; off >>= 1) mx = fmaxf(mx, __shfl_xor(mx, off, 64));
    float sum = 0.f;
#pragma unroll
    for (int t = 0; t < 8; ++t) { vals[t] = __expf(vals[t] - mx); sum += vals[t]; }
#pragma unroll
    for (int off = 32; off > 0; off >>= 1) sum += __shfl_xor(sum, off, 64);
    const float inv = 1.0f / sum;
    const long base = (((long)(b * 12 + h) * 512) + i) * 512;
#pragma unroll
    for (int t = 0; t < 8; ++t) sc[base + ln + (t << 6)] = vals[t] * inv;
  }
}

// ---------------------------------------------------------------------------
// Row LayerNorm over 768, eps inside sqrt (BERT style)
// ---------------------------------------------------------------------------
__global__ __launch_bounds__(256)
void ln_kernel(const float* __restrict__ x, const float* __restrict__ g,
               const float* __restrict__ bta, float* __restrict__ out)
{
  __shared__ float red[8];
  const long row = blockIdx.x;
  const int tid = threadIdx.x;
  const float* xr = x + row * 768;
  const float v0 = xr[tid], v1 = xr[tid + 256], v2 = xr[tid + 512];
  float sum = v0 + v1 + v2;
#pragma unroll
  for (int off = 32; off > 0; off >>= 1) sum += __shfl_xor(sum, off, 64);
  const int wv = tid >> 6, ln = tid & 63;
  if (ln == 0) red[wv] = sum;
  __syncthreads();
  const float mean = (red[0] + red[1] + red[2] + red[3]) * (1.0f / 768.0f);
  const float d0 = v0 - mean, d1 = v1 - mean, d2 = v2 - mean;
  float sq = d0 * d0 + d1 * d1 + d2 * d2;
#pragma unroll
  for (int off = 32; off > 0; off >>= 1) sq += __shfl_xor(sq, off, 64);
  if (ln == 0) red[4 + wv] = sq;
  __syncthreads();
  const float var = (red[4] + red[5] + red[6] + red[7]) * (1.0f / 768.0f);
  const float rstd = rsqrtf(var + 1e-12f);
  float* orow = out + row * 768;
  orow[tid]       = g[tid]       * d0 * rstd + bta[tid];
  orow[tid + 256] = g[tid + 256] * d1 * rstd + bta[tid + 256];
  orow[tid + 512] = g[tid + 512] * d2 * rstd + bta[tid + 512];
}

// ---------------------------------------------------------------------------
extern "C" void kernel_launch(void* const* d_in, const int* in_sizes, int n_in,
                              void* d_out, int out_size, void* d_ws, size_t ws_size,
                              hipStream_t stream)
{
  const float* hidden = (const float*)d_in[0];
  const float* graph  = (const float*)d_in[1];
  const float* rel    = (const float*)d_in[2];
  const float* Wq = (const float*)d_in[3];  const float* bq = (const float*)d_in[4];
  const float* Wk = (const float*)d_in[5];  const float* bk = (const float*)d_in[6];
  const float* Wv = (const float*)d_in[7];  const float* bv = (const float*)d_in[8];
  const float* Wr = (const float*)d_in[9];  const float* br = (const float*)d_in[10];
  const float* Wo = (const float*)d_in[11]; const float* bo = (const float*)d_in[12];
  const float* g1 = (const float*)d_in[13]; const float* b1 = (const float*)d_in[14];
  const float* Wi = (const float*)d_in[15]; const float* bi = (const float*)d_in[16];
  const float* Wf = (const float*)d_in[17]; const float* bff = (const float*)d_in[18];
  const float* g2 = (const float*)d_in[19]; const float* b2 = (const float*)d_in[20];
  float* out = (float*)d_out;

  const long HIDSZ = 2048L * 768L;       // 1,572,864
  const long SCSZ  = 48L * 512L * 512L;  // 12,582,912
  float* ws  = (float*)d_ws;
  float* q   = ws;                 // [2048,768]  (b,i,h,d)
  float* k_  = q   + HIDSZ;
  float* v_  = k_  + HIDSZ;
  float* qr  = v_  + HIDSZ;        // [2048,12,64] (b,i,h,r)
  float* qbr = qr  + HIDSZ;        // [2048,12]
  float* sc  = qbr + 2048L * 12L;  // [4,12,512,512] scores->probs
  float* ctx = sc  + SCSZ;         // [2048,768]
  // reuse: sc region is free after probs@v
  float* t1    = sc;               // pre-LN1
  float* attn  = sc + HIDSZ;       // post-LN1
  float* inter = sc + 2 * HIDSZ;   // [2048,3072]
  float* t2    = q;                // pre-LN2 (q free after scores GEMM)

  const dim3 blk(256);

  // QKV projections
  hipLaunchKernelGGL((gemm_kernel<false, 1>), dim3(16, 6, 1), blk, 0, stream,
    hidden, Wq, bq, (const float*)nullptr, q, 2048, 768, 768, 768, 768, 768,
    0L, 0L, 0L, 0L, 0L, 0L, 1, 1.0f);
  hipLaunchKernelGGL((gemm_kernel<false, 1>), dim3(16, 6, 1), blk, 0, stream,
    hidden, Wk, bk, (const float*)nullptr, k_, 2048, 768, 768, 768, 768, 768,
    0L, 0L, 0L, 0L, 0L, 0L, 1, 1.0f);
  hipLaunchKernelGGL((gemm_kernel<false, 1>), dim3(16, 6, 1), blk, 0, stream,
    hidden, Wv, bv, (const float*)nullptr, v_, 2048, 768, 768, 768, 768, 768,
    0L, 0L, 0L, 0L, 0L, 0L, 1, 1.0f);

  // qr = q @ Wr^T (tiny), qbr = q . br
  hipLaunchKernelGGL(qr_kernel, dim3(2048), blk, 0, stream, q, Wr, br, qr, qbr);

  // scores = (q @ k^T) / 8, batched over (b,h), NT
  hipLaunchKernelGGL((gemm_kernel<true, 0>), dim3(4, 4, 48), blk, 0, stream,
    q, k_, (const float*)nullptr, (const float*)nullptr, sc,
    512, 512, 64, 768, 768, 512,
    393216L, 64L, 393216L, 64L, 3145728L, 262144L, 12, 0.125f);

  // += (qr.rel + qbr)/8, mask, softmax (in-place)
  hipLaunchKernelGGL(relsm_kernel, dim3(2048), blk, 0, stream, rel, graph, qr, qbr, sc);

  // ctx = probs @ v, batched over (b,h), NN
  hipLaunchKernelGGL((gemm_kernel<false, 0>), dim3(4, 1, 48), blk, 0, stream,
    sc, v_, (const float*)nullptr, (const float*)nullptr, ctx,
    512, 64, 512, 512, 768, 768,
    3145728L, 262144L, 393216L, 64L, 393216L, 64L, 12, 1.0f);

  // t1 = ctx @ Wo + bo + hidden ; attn = LN(t1)
  hipLaunchKernelGGL((gemm_kernel<false, 2>), dim3(16, 6, 1), blk, 0, stream,
    ctx, Wo, bo, hidden, t1, 2048, 768, 768, 768, 768, 768,
    0L, 0L, 0L, 0L, 0L, 0L, 1, 1.0f);
  hipLaunchKernelGGL(ln_kernel, dim3(2048), blk, 0, stream, t1, g1, b1, attn);

  // inter = gelu(attn @ Wi + bi)
  hipLaunchKernelGGL((gemm_kernel<false, 3>), dim3(16, 24, 1), blk, 0, stream,
    attn, Wi, bi, (const float*)nullptr, inter, 2048, 3072, 768, 768, 3072, 3072,
    0L, 0L, 0L, 0L, 0L, 0L, 1, 1.0f);

  // t2 = inter @ Wf + bf + attn ; out = LN(t2)
  hipLaunchKernelGGL((gemm_kernel<false, 2>), dim3(16, 6, 1), blk, 0, stream,
    inter, Wf, bff, attn, t2, 2048, 768, 3072, 3072, 768, 768,
    0L, 0L, 0L, 0L, 0L, 0L, 1, 1.0f);
  hipLaunchKernelGGL(ln_kernel, dim3(2048), blk, 0, stream, t2, g2, b2, out);
}

// Round 2
// 267.736 us; speedup vs baseline: 4.8177x; 4.8177x over previous
//
#include <hip/hip_runtime.h>
#include <math.h>

typedef float f32x4 __attribute__((ext_vector_type(4)));
typedef _Float16 half8 __attribute__((ext_vector_type(8)));
typedef _Float16 half4 __attribute__((ext_vector_type(4)));

__device__ __forceinline__ void gload16(const void* gsrc, void* ldst) {
  __builtin_amdgcn_global_load_lds(
      (const __attribute__((address_space(1))) void*)gsrc,
      (__attribute__((address_space(3))) void*)ldst, 16, 0, 0);
}

// ---------------------------------------------------------------------------
// f16 MFMA GEMM. A: M x K row-major f16 (lda). B: N x K row-major f16 (ldb)
// ("NT" form -- all weights pre-transposed). BM=32*NI, BN=32*NJ, BK=32,
// 4 waves in 2x2. All dims divide tiles exactly (no bounds checks).
// EPI: 0=QKV(q/k f16 (b,h,s,d); v f16 transposed (b,h,d,s); bias by z)
//      1=f16 out, z-linear (scores)
//      2=PV -> ctx16 (b,s,h,d)
//      3=f32 out + bias + residual
//      4=f16 out + bias + gelu
// ---------------------------------------------------------------------------
template<int NI, int NJ, int EPI>
__global__ __launch_bounds__(256)
void gemm16(const _Float16* __restrict__ Ag, const _Float16* __restrict__ Bg,
            const float* __restrict__ bias0, const float* __restrict__ bias1,
            const float* __restrict__ bias2, const float* __restrict__ res,
            float* __restrict__ outf, _Float16* __restrict__ oh0,
            _Float16* __restrict__ oh1, _Float16* __restrict__ oh2,
            int M, int N, int K, int lda, int ldb, int ldc,
            long sAz, long sBz, long sOz, float alpha)
{
  constexpr int BM = 32 * NI, BN = 32 * NJ;
  __shared__ __align__(16) _Float16 As[BM][32];
  __shared__ __align__(16) _Float16 Bs[BN][32];

  const int z = blockIdx.z;
  const _Float16* A = Ag + z * sAz;
  const _Float16* B = Bg + z * sBz;

  const int tid = threadIdx.x, lane = tid & 63, wid = tid >> 6;
  const int m0 = blockIdx.x * BM, n0 = blockIdx.y * BN;
  const int l15 = lane & 15, lk = (lane >> 4) * 8;
  const int wm = (wid >> 1) * (16 * NI), wn = (wid & 1) * (16 * NJ);
  const int lr = lane >> 2, lc = (lane & 3) * 8;   // staging: 16 rows/wave-load

  f32x4 acc[NI][NJ] = {};

  for (int k0 = 0; k0 < K; k0 += 32) {
    __syncthreads();
#pragma unroll
    for (int g = wid; g < BM / 16; g += 4)
      gload16(A + (long)(m0 + g * 16 + lr) * lda + k0 + lc, &As[g * 16][0]);
#pragma unroll
    for (int g = wid; g < BN / 16; g += 4)
      gload16(B + (long)(n0 + g * 16 + lr) * ldb + k0 + lc, &Bs[g * 16][0]);
    __syncthreads();

    half8 af[NI], bfr[NJ];
#pragma unroll
    for (int i = 0; i < NI; ++i)
      af[i] = *reinterpret_cast<const half8*>(&As[wm + i * 16 + l15][lk]);
#pragma unroll
    for (int j = 0; j < NJ; ++j)
      bfr[j] = *reinterpret_cast<const half8*>(&Bs[wn + j * 16 + l15][lk]);
#pragma unroll
    for (int i = 0; i < NI; ++i)
#pragma unroll
      for (int j = 0; j < NJ; ++j)
        acc[i][j] = __builtin_amdgcn_mfma_f32_16x16x32_f16(af[i], bfr[j], acc[i][j], 0, 0, 0);
  }

#pragma unroll
  for (int i = 0; i < NI; ++i) {
#pragma unroll
    for (int j = 0; j < NJ; ++j) {
#pragma unroll
      for (int r = 0; r < 4; ++r) {
        const int row = m0 + wm + i * 16 + ((lane >> 4) << 2) + r;
        const int col = n0 + wn + j * 16 + l15;
        float v = acc[i][j][r] * alpha;
        if constexpr (EPI == 0) {
          const float* bb = (z == 0) ? bias0 : (z == 1) ? bias1 : bias2;
          v += bb[col];
          const int b = row >> 9, sI = row & 511, h = col >> 6, d = col & 63;
          if (z == 2)
            oh2[((long)((b * 12 + h) * 64 + d)) * 512 + sI] = (_Float16)v;
          else {
            _Float16* dst = (z == 0) ? oh0 : oh1;
            dst[((long)((b * 12 + h) * 512 + sI)) * 64 + d] = (_Float16)v;
          }
        } else if constexpr (EPI == 1) {
          oh0[z * sOz + (long)row * ldc + col] = (_Float16)v;
        } else if constexpr (EPI == 2) {
          const int zb = z / 12, zh = z - 12 * zb;
          oh0[((long)(zb * 512 + row)) * 768 + zh * 64 + col] = (_Float16)v;
        } else if constexpr (EPI == 3) {
          v += bias0[col] + res[(long)row * ldc + col];
          outf[(long)row * ldc + col] = v;
        } else if constexpr (EPI == 4) {
          v += bias0[col];
          v = 0.5f * v * (1.0f + erff(v * 0.70710678118654752440f));
          oh0[(long)row * ldc + col] = (_Float16)v;
        }
      }
    }
  }
}

// ---------------------------------------------------------------------------
// Transpose + f32->f16: dst[c][r] = src[r][c]. z picks among up to 4 matrices.
// ---------------------------------------------------------------------------
__global__ __launch_bounds__(256)
void convT(const float* s0, const float* s1, const float* s2, const float* s3,
           _Float16* d0, _Float16* d1, _Float16* d2, _Float16* d3, int R, int C)
{
  const float* src; _Float16* dst;
  switch (blockIdx.z) {
    case 0: src = s0; dst = d0; break;
    case 1: src = s1; dst = d1; break;
    case 2: src = s2; dst = d2; break;
    default: src = s3; dst = d3; break;
  }
  __shared__ float t[32][33];
  const int tid = threadIdx.x, tx = tid & 31, ty = tid >> 5;
  const int c0 = blockIdx.x * 32, r0 = blockIdx.y * 32;
#pragma unroll
  for (int yy = ty; yy < 32; yy += 8)
    t[yy][tx] = src[(long)(r0 + yy) * C + c0 + tx];
  __syncthreads();
#pragma unroll
  for (int yy = ty; yy < 32; yy += 8)
    dst[(long)(c0 + yy) * R + r0 + tx] = (_Float16)t[tx][yy];
}

// flat f32 -> f16
__global__ __launch_bounds__(256)
void conv16(const float* __restrict__ in, _Float16* __restrict__ out, long n4)
{
  const long i = (long)blockIdx.x * 256 + threadIdx.x;
  if (i < n4) {
    const float4 v = reinterpret_cast<const float4*>(in)[i];
    half4 h = {(_Float16)v.x, (_Float16)v.y, (_Float16)v.z, (_Float16)v.w};
    *reinterpret_cast<half4*>(out + i * 4) = h;
  }
}

// ---------------------------------------------------------------------------
// qr[b,i,h,r] = sum_d q[b,h,i,d] * Wr[r,d];  qbr[b,i,h] = sum_d q*br
// ---------------------------------------------------------------------------
__global__ __launch_bounds__(256)
void qr_kernel(const _Float16* __restrict__ q16, const float* __restrict__ Wr,
               const float* __restrict__ br, float* __restrict__ qr,
               float* __restrict__ qbr)
{
  __shared__ float qrow[12][64];
  __shared__ float wr[64][65];
  __shared__ float brs[64];
  const long bi = blockIdx.x;
  const int b = (int)(bi >> 9), i = (int)(bi & 511);
  const int tid = threadIdx.x;
  for (int t = tid; t < 768; t += 256) {
    const int h = t >> 6, d = t & 63;
    qrow[h][d] = (float)q16[((long)((b * 12 + h) * 512 + i)) * 64 + d];
  }
  for (int t = tid; t < 4096; t += 256) wr[t >> 6][t & 63] = Wr[t];
  if (tid < 64) brs[tid] = br[tid];
  __syncthreads();
  for (int o = tid; o < 768; o += 256) {
    const int h = o >> 6, r = o & 63;
    float s = 0.f;
#pragma unroll 8
    for (int d = 0; d < 64; ++d) s += qrow[h][d] * wr[r][d];
    qr[bi * 768 + o] = s;
  }
  if (tid < 12) {
    float s = 0.f;
#pragma unroll 8
    for (int d = 0; d < 64; ++d) s += qrow[tid][d] * brs[d];
    qbr[bi * 12 + tid] = s;
  }
}

// ---------------------------------------------------------------------------
// Per (b,i): s[h][j] = scores16 + qbr/8 + mask; s += (qr . rel)/8 via MFMA
// while streaming rel[b,i,:,:] once; softmax over j; write probs f16 in-place.
// ---------------------------------------------------------------------------
__global__ __launch_bounds__(256)
void relsm2(const float* __restrict__ rel, const float* __restrict__ graph,
            const float* __restrict__ qr, const float* __restrict__ qbr,
            _Float16* __restrict__ sc)   // in: scores f16, out: probs f16
{
  __shared__ float s[12][512];
  __shared__ __align__(16) _Float16 rt[64][72];   // padded: 144B rows (16B mult)
  __shared__ float gl[512];
  __shared__ float qb8[12];

  const int bi = blockIdx.x;
  const int b = bi >> 9, i = bi & 511;
  const int tid = threadIdx.x, lane = tid & 63, wid = tid >> 6;
  const int l15 = lane & 15, lk = (lane >> 4) * 8;

  // A-fragments (qr row h=l15, k-slots lk.. and 32+lk..)
  half8 qa0, qa1;
  {
    const int h = l15;
    if (h < 12) {
      const float* qp = qr + (long)bi * 768 + h * 64 + lk;
#pragma unroll
      for (int e = 0; e < 8; ++e) { qa0[e] = (_Float16)qp[e]; qa1[e] = (_Float16)qp[32 + e]; }
    } else {
#pragma unroll
      for (int e = 0; e < 8; ++e) { qa0[e] = (_Float16)0.f; qa1[e] = (_Float16)0.f; }
    }
  }
  if (tid < 12) qb8[tid] = qbr[(long)bi * 12 + tid] * 0.125f;
  for (int t = tid; t < 512; t += 256) gl[t] = graph[(long)bi * 512 + t];
  __syncthreads();
  for (int t = tid; t < 6144; t += 256) {
    const int h = t >> 9, j = t & 511;
    s[h][j] = (float)sc[((long)((b * 12 + h) * 512 + i)) * 512 + j]
            + qb8[h] + (1.0f - gl[j]) * (-1.0e9f);
  }

  for (int jt = 0; jt < 512; jt += 64) {
    __syncthreads();
    const float* rb = rel + ((long)bi * 512 + jt) * 64;
#pragma unroll
    for (int p = 0; p < 4; ++p) {
      const int idx4 = (p * 256 + tid) * 4;
      const float4 v = *reinterpret_cast<const float4*>(rb + idx4);
      const int j = idx4 >> 6, r = idx4 & 63;
      half4 h4 = {(_Float16)v.x, (_Float16)v.y, (_Float16)v.z, (_Float16)v.w};
      *reinterpret_cast<half4*>(&rt[j][r]) = h4;
    }
    __syncthreads();
    half8 b0 = *reinterpret_cast<const half8*>(&rt[wid * 16 + l15][lk]);
    half8 b1 = *reinterpret_cast<const half8*>(&rt[wid * 16 + l15][32 + lk]);
    f32x4 acc = {};
    acc = __builtin_amdgcn_mfma_f32_16x16x32_f16(qa0, b0, acc, 0, 0, 0);
    acc = __builtin_amdgcn_mfma_f32_16x16x32_f16(qa1, b1, acc, 0, 0, 0);
#pragma unroll
    for (int r = 0; r < 4; ++r) {
      const int h = ((lane >> 4) << 2) + r;
      if (h < 12) s[h][jt + wid * 16 + l15] += acc[r] * 0.125f;
    }
  }
  __syncthreads();

  for (int h = wid; h < 12; h += 4) {
    float vals[8];
    float mx = -3.4e38f;
#pragma unroll
    for (int t = 0; t < 8; ++t) {
      vals[t] = s[h][lane + (t << 6)];
      mx = fmaxf(mx, vals[t]);
    }
#pragma unroll
    for (int off = 32; off > 0; off >>= 1) mx = fmaxf(mx, __shfl_xor(mx, off, 64));
    float sum = 0.f;
#pragma unroll
    for (int t = 0; t < 8; ++t) { vals[t] = __expf(vals[t] - mx); sum += vals[t]; }
#pragma unroll
    for (int off = 32; off > 0; off >>= 1) sum += __shfl_xor(sum, off, 64);
    const float inv = 1.0f / sum;
    const long base = ((long)((b * 12 + h) * 512 + i)) * 512;
#pragma unroll
    for (int t = 0; t < 8; ++t) sc[base + lane + (t << 6)] = (_Float16)(vals[t] * inv);
  }
}

// ---------------------------------------------------------------------------
// Row LayerNorm over 768 (eps inside sqrt). Optional f16 secondary output.
// ---------------------------------------------------------------------------
__global__ __launch_bounds__(256)
void ln_kernel(const float* __restrict__ x, const float* __restrict__ g,
               const float* __restrict__ bta, float* __restrict__ out,
               _Float16* __restrict__ out16)
{
  __shared__ float red[8];
  const long row = blockIdx.x;
  const int tid = threadIdx.x;
  const float* xr = x + row * 768;
  const float v0 = xr[tid], v1 = xr[tid + 256], v2 = xr[tid + 512];
  float sum = v0 + v1 + v2;
#pragma unroll
  for (int off = 32; off > 0; off >>= 1) sum += __shfl_xor(sum, off, 64);
  const int wv = tid >> 6, ln = tid & 63;
  if (ln == 0) red[wv] = sum;
  __syncthreads();
  const float mean = (red[0] + red[1] + red[2] + red[3]) * (1.0f / 768.0f);
  const float d0 = v0 - mean, d1 = v1 - mean, d2 = v2 - mean;
  float sq = d0 * d0 + d1 * d1 + d2 * d2;
#pragma unroll
  for (int off = 32; off > 0; off >>= 1) sq += __shfl_xor(sq, off, 64);
  if (ln == 0) red[4 + wv] = sq;
  __syncthreads();
  const float var = (red[4] + red[5] + red[6] + red[7]) * (1.0f / 768.0f);
  const float rstd = rsqrtf(var + 1e-12f);
  const float o0 = g[tid] * d0 * rstd + bta[tid];
  const float o1 = g[tid + 256] * d1 * rstd + bta[tid + 256];
  const float o2 = g[tid + 512] * d2 * rstd + bta[tid + 512];
  float* orow = out + row * 768;
  orow[tid] = o0; orow[tid + 256] = o1; orow[tid + 512] = o2;
  if (out16) {
    _Float16* hrow = out16 + row * 768;
    hrow[tid] = (_Float16)o0; hrow[tid + 256] = (_Float16)o1; hrow[tid + 512] = (_Float16)o2;
  }
}

// ---------------------------------------------------------------------------
extern "C" void kernel_launch(void* const* d_in, const int* in_sizes, int n_in,
                              void* d_out, int out_size, void* d_ws, size_t ws_size,
                              hipStream_t stream)
{
  const float* hidden = (const float*)d_in[0];
  const float* graph  = (const float*)d_in[1];
  const float* rel    = (const float*)d_in[2];
  const float* Wq = (const float*)d_in[3];  const float* bq = (const float*)d_in[4];
  const float* Wk = (const float*)d_in[5];  const float* bk = (const float*)d_in[6];
  const float* Wv = (const float*)d_in[7];  const float* bv = (const float*)d_in[8];
  const float* Wr = (const float*)d_in[9];  const float* br = (const float*)d_in[10];
  const float* Wo = (const float*)d_in[11]; const float* bo = (const float*)d_in[12];
  const float* g1 = (const float*)d_in[13]; const float* b1 = (const float*)d_in[14];
  const float* Wi = (const float*)d_in[15]; const float* bi = (const float*)d_in[16];
  const float* Wf = (const float*)d_in[17]; const float* bff = (const float*)d_in[18];
  const float* g2 = (const float*)d_in[19]; const float* b2 = (const float*)d_in[20];
  float* out = (float*)d_out;

  // ---- workspace carving (bytes, 256B-aligned blocks)
  char* base = (char*)d_ws;
  size_t off = 0;
  auto carve = [&](size_t bytes) { void* p = base + off; off += (bytes + 255) & ~255UL; return p; };
  _Float16* h16   = (_Float16*)carve(2048L * 768 * 2);
  _Float16* w4t   = (_Float16*)carve(4L * 768 * 768 * 2);   // WqT,WkT,WvT,WoT
  _Float16* wiT   = (_Float16*)carve(3072L * 768 * 2);
  _Float16* wfT   = (_Float16*)carve(768L * 3072 * 2);
  _Float16* q16   = (_Float16*)carve(2048L * 768 * 2);      // (b,h,s,d)
  _Float16* k16   = (_Float16*)carve(2048L * 768 * 2);      // (b,h,s,d)
  _Float16* v16t  = (_Float16*)carve(2048L * 768 * 2);      // (b,h,d,s)
  _Float16* sc16  = (_Float16*)carve(48L * 512 * 512 * 2);  // scores -> probs
  float*    qr    = (float*)carve(2048L * 768 * 4);
  float*    qbr   = (float*)carve(2048L * 12 * 4);
  _Float16* ctx16 = (_Float16*)carve(2048L * 768 * 2);      // (b,s,h,d)
  float*    t1    = (float*)carve(2048L * 768 * 4);
  float*    attn  = (float*)carve(2048L * 768 * 4);
  _Float16* attn16= (_Float16*)carve(2048L * 768 * 2);
  _Float16* inter16=(_Float16*)carve(2048L * 3072 * 2);
  float*    t2    = (float*)carve(2048L * 768 * 4);

  const dim3 blk(256);
  const long W44 = 768L * 768;

  // ---- operand conversion
  hipLaunchKernelGGL(convT, dim3(24, 24, 4), blk, 0, stream,
    Wq, Wk, Wv, Wo, w4t, w4t + W44, w4t + 2 * W44, w4t + 3 * W44, 768, 768);
  hipLaunchKernelGGL(convT, dim3(96, 24, 1), blk, 0, stream,
    Wi, Wi, Wi, Wi, wiT, wiT, wiT, wiT, 768, 3072);
  hipLaunchKernelGGL(convT, dim3(24, 96, 1), blk, 0, stream,
    Wf, Wf, Wf, Wf, wfT, wfT, wfT, wfT, 3072, 768);
  hipLaunchKernelGGL(conv16, dim3(1536), blk, 0, stream, hidden, h16, 2048L * 768 / 4);

  // ---- QKV fused (z=0,1,2): 128x64 tiles, grid 16x12x3 = 576 blocks
  hipLaunchKernelGGL((gemm16<4, 2, 0>), dim3(16, 12, 3), blk, 0, stream,
    h16, w4t, bq, bk, bv, (const float*)nullptr,
    (float*)nullptr, q16, k16, v16t,
    2048, 768, 768, 768, 768, 768, 0L, W44, 0L, 1.0f);

  hipLaunchKernelGGL(qr_kernel, dim3(2048), blk, 0, stream, q16, Wr, br, qr, qbr);

  // ---- scores = (q @ k^T)/8 f16, z=(b,h): 128x128, grid 4x4x48
  hipLaunchKernelGGL((gemm16<4, 4, 1>), dim3(4, 4, 48), blk, 0, stream,
    q16, k16, (const float*)nullptr, (const float*)nullptr, (const float*)nullptr,
    (const float*)nullptr, (float*)nullptr, sc16, (_Float16*)nullptr, (_Float16*)nullptr,
    512, 512, 64, 64, 64, 512, 32768L, 32768L, 262144L, 0.125f);

  // ---- + rel term + mask + softmax (in-place f16)
  hipLaunchKernelGGL(relsm2, dim3(2048), blk, 0, stream, rel, graph, qr, qbr, sc16);

  // ---- ctx = probs @ v : 64x64, grid 8x1x48
  hipLaunchKernelGGL((gemm16<2, 2, 2>), dim3(8, 1, 48), blk, 0, stream,
    sc16, v16t, (const float*)nullptr, (const float*)nullptr, (const float*)nullptr,
    (const float*)nullptr, (float*)nullptr, ctx16, (_Float16*)nullptr, (_Float16*)nullptr,
    512, 64, 512, 512, 512, 768, 262144L, 32768L, 0L, 1.0f);

  // ---- t1 = ctx @ Wo + bo + hidden : 64x64, grid 32x12
  hipLaunchKernelGGL((gemm16<2, 2, 3>), dim3(32, 12, 1), blk, 0, stream,
    ctx16, w4t + 3 * W44, bo, (const float*)nullptr, (const float*)nullptr, hidden,
    t1, (_Float16*)nullptr, (_Float16*)nullptr, (_Float16*)nullptr,
    2048, 768, 768, 768, 768, 768, 0L, 0L, 0L, 1.0f);
  hipLaunchKernelGGL(ln_kernel, dim3(2048), blk, 0, stream, t1, g1, b1, attn, attn16);

  // ---- inter = gelu(attn @ Wi + bi) : 128x128, grid 16x24
  hipLaunchKernelGGL((gemm16<4, 4, 4>), dim3(16, 24, 1), blk, 0, stream,
    attn16, wiT, bi, (const float*)nullptr, (const float*)nullptr, (const float*)nullptr,
    (float*)nullptr, inter16, (_Float16*)nullptr, (_Float16*)nullptr,
    2048, 3072, 768, 768, 768, 3072, 0L, 0L, 0L, 1.0f);

  // ---- t2 = inter @ Wf + bf + attn : 64x64, grid 32x12
  hipLaunchKernelGGL((gemm16<2, 2, 3>), dim3(32, 12, 1), blk, 0, stream,
    inter16, wfT, bff, (const float*)nullptr, (const float*)nullptr, attn,
    t2, (_Float16*)nullptr, (_Float16*)nullptr, (_Float16*)nullptr,
    2048, 768, 3072, 3072, 3072, 768, 0L, 0L, 0L, 1.0f);
  hipLaunchKernelGGL(ln_kernel, dim3(2048), blk, 0, stream, t2, g2, b2, out, (_Float16*)nullptr);
}

// Round 3
// 264.468 us; speedup vs baseline: 4.8772x; 1.0124x over previous
//
#include <hip/hip_runtime.h>
#include <math.h>

typedef float f32x4 __attribute__((ext_vector_type(4)));
typedef _Float16 half8 __attribute__((ext_vector_type(8)));
typedef _Float16 half4 __attribute__((ext_vector_type(4)));

__device__ __forceinline__ void gload16(const void* gsrc, void* ldst) {
  __builtin_amdgcn_global_load_lds(
      (const __attribute__((address_space(1))) void*)gsrc,
      (__attribute__((address_space(3))) void*)ldst, 16, 0, 0);
}

// ---------------------------------------------------------------------------
// f16 MFMA GEMM, double-buffered LDS (one barrier per K-step), XOR-swizzled
// LDS banks (swizzle applied on the GLOBAL source so global_load_lds's linear
// lane->LDS mapping stays intact; ds_read applies the same swizzle).
// A: M x K row-major f16 (lda). B: N x K row-major f16 (ldb). BK=32.
// 4 waves 2x2. All dims divide tiles exactly.
// EPI: 0=QKV(q/k f16 (b,h,s,d); v f16 transposed (b,h,d,s); bias by z)
//      1=f16 out, z-linear (scores)
//      2=PV -> ctx16 (b,s,h,d)
//      3=f32 out + bias + residual
//      4=f16 out + bias + gelu
// ---------------------------------------------------------------------------
template<int NI, int NJ, int EPI>
__global__ __launch_bounds__(256)
void gemm16(const _Float16* __restrict__ Ag, const _Float16* __restrict__ Bg,
            const float* __restrict__ bias0, const float* __restrict__ bias1,
            const float* __restrict__ bias2, const float* __restrict__ res,
            float* __restrict__ outf, _Float16* __restrict__ oh0,
            _Float16* __restrict__ oh1, _Float16* __restrict__ oh2,
            int M, int N, int K, int lda, int ldb, int ldc,
            long sAz, long sBz, long sOz, float alpha)
{
  constexpr int BM = 32 * NI, BN = 32 * NJ;
  constexpr int GA = BM / 64, GB = BN / 64;   // 16-row groups per wave
  __shared__ __align__(16) _Float16 As[2][BM][32];
  __shared__ __align__(16) _Float16 Bs[2][BN][32];

  const int z = blockIdx.z;
  const _Float16* A = Ag + (long)z * sAz;
  const _Float16* B = Bg + (long)z * sBz;

  const int tid = threadIdx.x, lane = tid & 63, wid = tid >> 6;
  const int m0 = blockIdx.x * BM, n0 = blockIdx.y * BN;
  const int l15 = lane & 15;
  const int wm = (wid >> 1) * (16 * NI), wn = (wid & 1) * (16 * NJ);
  const int lr = lane >> 2;                             // row within 16-group
  const int scol = ((lane & 3) ^ (lane >> 4)) * 8;      // pre-swizzled src col
  const int fcol = ((lane >> 4) ^ (l15 >> 2)) * 8;      // swizzled read col

  f32x4 acc[NI][NJ] = {};

  auto stage = [&](int bf, int kk) {
#pragma unroll
    for (int gg = 0; gg < GA; ++gg) {
      const int g = gg * 4 + wid;
      gload16(A + (long)(m0 + g * 16 + lr) * lda + kk + scol, &As[bf][g * 16][0]);
    }
#pragma unroll
    for (int gg = 0; gg < GB; ++gg) {
      const int g = gg * 4 + wid;
      gload16(B + (long)(n0 + g * 16 + lr) * ldb + kk + scol, &Bs[bf][g * 16][0]);
    }
  };

  stage(0, 0);
  asm volatile("s_waitcnt vmcnt(0)" ::: "memory");
  __syncthreads();

  int buf = 0;
  for (int k0 = 0; k0 < K; k0 += 32) {
    if (k0 + 32 < K) stage(buf ^ 1, k0 + 32);   // prefetch next tile (async)
    half8 af[NI], bfr[NJ];
#pragma unroll
    for (int i = 0; i < NI; ++i)
      af[i] = *reinterpret_cast<const half8*>(&As[buf][wm + i * 16 + l15][fcol]);
#pragma unroll
    for (int j = 0; j < NJ; ++j)
      bfr[j] = *reinterpret_cast<const half8*>(&Bs[buf][wn + j * 16 + l15][fcol]);
#pragma unroll
    for (int i = 0; i < NI; ++i)
#pragma unroll
      for (int j = 0; j < NJ; ++j)
        acc[i][j] = __builtin_amdgcn_mfma_f32_16x16x32_f16(af[i], bfr[j], acc[i][j], 0, 0, 0);
    asm volatile("s_waitcnt vmcnt(0)" ::: "memory");  // next tile landed
    __syncthreads();
    buf ^= 1;
  }

#pragma unroll
  for (int i = 0; i < NI; ++i) {
#pragma unroll
    for (int j = 0; j < NJ; ++j) {
      const int row0 = m0 + wm + i * 16 + ((lane >> 4) << 2);
      const int col = n0 + wn + j * 16 + l15;
      if constexpr (EPI == 0) {
        const float* bb = (z == 0) ? bias0 : (z == 1) ? bias1 : bias2;
        const float bv = bb[col];
        const int b = row0 >> 9, h = col >> 6, d = col & 63;
        if (z == 2) {
          half4 pk;
#pragma unroll
          for (int r = 0; r < 4; ++r) pk[r] = (_Float16)(acc[i][j][r] + bv);
          *reinterpret_cast<half4*>(
              &oh2[((long)((b * 12 + h) * 64 + d)) * 512 + (row0 & 511)]) = pk;
        } else {
          _Float16* dst = (z == 0) ? oh0 : oh1;
#pragma unroll
          for (int r = 0; r < 4; ++r)
            dst[((long)((b * 12 + h) * 512 + (row0 & 511) + r)) * 64 + d] =
                (_Float16)(acc[i][j][r] + bv);
        }
      } else {
#pragma unroll
        for (int r = 0; r < 4; ++r) {
          const int row = row0 + r;
          float v = acc[i][j][r] * alpha;
          if constexpr (EPI == 1) {
            oh0[(long)z * sOz + (long)row * ldc + col] = (_Float16)v;
          } else if constexpr (EPI == 2) {
            const int zb = z / 12, zh = z - 12 * zb;
            oh0[((long)(zb * 512 + row)) * 768 + zh * 64 + col] = (_Float16)v;
          } else if constexpr (EPI == 3) {
            v += bias0[col] + res[(long)row * ldc + col];
            outf[(long)row * ldc + col] = v;
          } else if constexpr (EPI == 4) {
            v += bias0[col];
            v = 0.5f * v * (1.0f + erff(v * 0.70710678118654752440f));
            oh0[(long)row * ldc + col] = (_Float16)v;
          }
        }
      }
    }
  }
}

// ---------------------------------------------------------------------------
// Transpose + f32->f16: dst[c][r] = src[r][c]. z picks among up to 4 matrices.
// ---------------------------------------------------------------------------
__global__ __launch_bounds__(256)
void convT(const float* s0, const float* s1, const float* s2, const float* s3,
           _Float16* d0, _Float16* d1, _Float16* d2, _Float16* d3, int R, int C)
{
  const float* src; _Float16* dst;
  switch (blockIdx.z) {
    case 0: src = s0; dst = d0; break;
    case 1: src = s1; dst = d1; break;
    case 2: src = s2; dst = d2; break;
    default: src = s3; dst = d3; break;
  }
  __shared__ float t[32][33];
  const int tid = threadIdx.x, tx = tid & 31, ty = tid >> 5;
  const int c0 = blockIdx.x * 32, r0 = blockIdx.y * 32;
#pragma unroll
  for (int yy = ty; yy < 32; yy += 8)
    t[yy][tx] = src[(long)(r0 + yy) * C + c0 + tx];
  __syncthreads();
#pragma unroll
  for (int yy = ty; yy < 32; yy += 8)
    dst[(long)(c0 + yy) * R + r0 + tx] = (_Float16)t[tx][yy];
}

// flat f32 -> f16
__global__ __launch_bounds__(256)
void conv16(const float* __restrict__ in, _Float16* __restrict__ out, long n4)
{
  const long i = (long)blockIdx.x * 256 + threadIdx.x;
  if (i < n4) {
    const float4 v = reinterpret_cast<const float4*>(in)[i];
    half4 h = {(_Float16)v.x, (_Float16)v.y, (_Float16)v.z, (_Float16)v.w};
    *reinterpret_cast<half4*>(out + i * 4) = h;
  }
}

// ---------------------------------------------------------------------------
// qr16[b,i,h,r] = sum_d q[b,h,i,d] * Wr[r,d];  qbr[b,i,h] = sum_d q*br
// ---------------------------------------------------------------------------
__global__ __launch_bounds__(256)
void qr_kernel(const _Float16* __restrict__ q16, const float* __restrict__ Wr,
               const float* __restrict__ br, _Float16* __restrict__ qr16,
               float* __restrict__ qbr)
{
  __shared__ float qrow[12][64];
  __shared__ float wr[64][65];
  __shared__ float brs[64];
  const long bi = blockIdx.x;
  const int b = (int)(bi >> 9), i = (int)(bi & 511);
  const int tid = threadIdx.x;
  for (int t = tid; t < 768; t += 256) {
    const int h = t >> 6, d = t & 63;
    qrow[h][d] = (float)q16[((long)((b * 12 + h) * 512 + i)) * 64 + d];
  }
  for (int t = tid; t < 4096; t += 256) wr[t >> 6][t & 63] = Wr[t];
  if (tid < 64) brs[tid] = br[tid];
  __syncthreads();
  for (int o = tid; o < 768; o += 256) {
    const int h = o >> 6, r = o & 63;
    float s = 0.f;
#pragma unroll 8
    for (int d = 0; d < 64; ++d) s += qrow[h][d] * wr[r][d];
    qr16[bi * 768 + o] = (_Float16)s;
  }
  if (tid < 12) {
    float s = 0.f;
#pragma unroll 8
    for (int d = 0; d < 64; ++d) s += qrow[tid][d] * brs[d];
    qbr[bi * 12 + tid] = s;
  }
}

// ---------------------------------------------------------------------------
// Per (b,i): s[h][j] = scores16 + qbr/8 + mask; s += (qr . rel)/8 via MFMA
// with rel B-fragments loaded straight from global (consumed exactly once,
// no LDS staging, no barriers in the streaming loop); softmax; probs f16.
// ---------------------------------------------------------------------------
__global__ __launch_bounds__(256)
void relsm2(const float* __restrict__ rel, const float* __restrict__ graph,
            const _Float16* __restrict__ qr16, const float* __restrict__ qbr,
            _Float16* __restrict__ sc)   // in: scores f16, out: probs f16
{
  __shared__ float s[12][512];
  __shared__ float gl[512];
  __shared__ float qb8[12];

  const int bi = blockIdx.x;
  const int b = bi >> 9, i = bi & 511;
  const int tid = threadIdx.x, lane = tid & 63, wid = tid >> 6;
  const int l15 = lane & 15, lk = (lane >> 4) * 8;

  half8 qa0 = {}, qa1 = {};
  if (l15 < 12) {
    qa0 = *reinterpret_cast<const half8*>(qr16 + (long)bi * 768 + l15 * 64 + lk);
    qa1 = *reinterpret_cast<const half8*>(qr16 + (long)bi * 768 + l15 * 64 + 32 + lk);
  }
  if (tid < 12) qb8[tid] = qbr[(long)bi * 12 + tid] * 0.125f;
  for (int t = tid; t < 512; t += 256) gl[t] = graph[(long)bi * 512 + t];
  __syncthreads();
  for (int t = tid; t < 6144; t += 256) {
    const int h = t >> 9, j = t & 511;
    s[h][j] = (float)sc[(((long)(b * 12 + h) * 512) + i) * 512 + j]
            + qb8[h] + (1.0f - gl[j]) * (-1.0e9f);
  }
  __syncthreads();

  const long rbase = ((long)bi * 512 + wid * 16 + l15) * 64 + lk;
  const int jj0 = wid * 16 + l15;
  for (int jt = 0; jt < 512; jt += 64) {
    const float* rp = rel + rbase + (long)jt * 64;
    const float4 v0 = *reinterpret_cast<const float4*>(rp);
    const float4 v1 = *reinterpret_cast<const float4*>(rp + 4);
    const float4 v2 = *reinterpret_cast<const float4*>(rp + 32);
    const float4 v3 = *reinterpret_cast<const float4*>(rp + 36);
    half8 b0, b1;
    b0[0] = (_Float16)v0.x; b0[1] = (_Float16)v0.y; b0[2] = (_Float16)v0.z; b0[3] = (_Float16)v0.w;
    b0[4] = (_Float16)v1.x; b0[5] = (_Float16)v1.y; b0[6] = (_Float16)v1.z; b0[7] = (_Float16)v1.w;
    b1[0] = (_Float16)v2.x; b1[1] = (_Float16)v2.y; b1[2] = (_Float16)v2.z; b1[3] = (_Float16)v2.w;
    b1[4] = (_Float16)v3.x; b1[5] = (_Float16)v3.y; b1[6] = (_Float16)v3.z; b1[7] = (_Float16)v3.w;
    f32x4 acc = {};
    acc = __builtin_amdgcn_mfma_f32_16x16x32_f16(qa0, b0, acc, 0, 0, 0);
    acc = __builtin_amdgcn_mfma_f32_16x16x32_f16(qa1, b1, acc, 0, 0, 0);
#pragma unroll
    for (int r = 0; r < 4; ++r) {
      const int h = ((lane >> 4) << 2) + r;
      if (h < 12) s[h][jt + jj0] += acc[r] * 0.125f;
    }
  }
  __syncthreads();

  for (int h = wid; h < 12; h += 4) {
    float vals[8];
    float mx = -3.4e38f;
#pragma unroll
    for (int t = 0; t < 8; ++t) {
      vals[t] = s[h][lane + (t << 6)];
      mx = fmaxf(mx, vals[t]);
    }
#pragma unroll
    for (int off = 32; off > 0; off >>= 1) mx = fmaxf(mx, __shfl_xor(mx, off, 64));
    float sum = 0.f;
#pragma unroll
    for (int t = 0; t < 8; ++t) { vals[t] = __expf(vals[t] - mx); sum += vals[t]; }
#pragma unroll
    for (int off = 32; off > 0; off >>= 1) sum += __shfl_xor(sum, off, 64);
    const float inv = 1.0f / sum;
    const long base = ((long)((b * 12 + h) * 512 + i)) * 512;
#pragma unroll
    for (int t = 0; t < 8; ++t) sc[base + lane + (t << 6)] = (_Float16)(vals[t] * inv);
  }
}

// ---------------------------------------------------------------------------
// Row LayerNorm over 768 (eps inside sqrt). Optional f16 secondary output.
// ---------------------------------------------------------------------------
__global__ __launch_bounds__(256)
void ln_kernel(const float* __restrict__ x, const float* __restrict__ g,
               const float* __restrict__ bta, float* __restrict__ out,
               _Float16* __restrict__ out16)
{
  __shared__ float red[8];
  const long row = blockIdx.x;
  const int tid = threadIdx.x;
  const float* xr = x + row * 768;
  const float v0 = xr[tid], v1 = xr[tid + 256], v2 = xr[tid + 512];
  float sum = v0 + v1 + v2;
#pragma unroll
  for (int off = 32; off > 0; off >>= 1) sum += __shfl_xor(sum, off, 64);
  const int wv = tid >> 6, ln = tid & 63;
  if (ln == 0) red[wv] = sum;
  __syncthreads();
  const float mean = (red[0] + red[1] + red[2] + red[3]) * (1.0f / 768.0f);
  const float d0 = v0 - mean, d1 = v1 - mean, d2 = v2 - mean;
  float sq = d0 * d0 + d1 * d1 + d2 * d2;
#pragma unroll
  for (int off = 32; off > 0; off >>= 1) sq += __shfl_xor(sq, off, 64);
  if (ln == 0) red[4 + wv] = sq;
  __syncthreads();
  const float var = (red[4] + red[5] + red[6] + red[7]) * (1.0f / 768.0f);
  const float rstd = rsqrtf(var + 1e-12f);
  const float o0 = g[tid] * d0 * rstd + bta[tid];
  const float o1 = g[tid + 256] * d1 * rstd + bta[tid + 256];
  const float o2 = g[tid + 512] * d2 * rstd + bta[tid + 512];
  float* orow = out + row * 768;
  orow[tid] = o0; orow[tid + 256] = o1; orow[tid + 512] = o2;
  if (out16) {
    _Float16* hrow = out16 + row * 768;
    hrow[tid] = (_Float16)o0; hrow[tid + 256] = (_Float16)o1; hrow[tid + 512] = (_Float16)o2;
  }
}

// ---------------------------------------------------------------------------
extern "C" void kernel_launch(void* const* d_in, const int* in_sizes, int n_in,
                              void* d_out, int out_size, void* d_ws, size_t ws_size,
                              hipStream_t stream)
{
  const float* hidden = (const float*)d_in[0];
  const float* graph  = (const float*)d_in[1];
  const float* rel    = (const float*)d_in[2];
  const float* Wq = (const float*)d_in[3];  const float* bq = (const float*)d_in[4];
  const float* Wk = (const float*)d_in[5];  const float* bk = (const float*)d_in[6];
  const float* Wv = (const float*)d_in[7];  const float* bv = (const float*)d_in[8];
  const float* Wr = (const float*)d_in[9];  const float* br = (const float*)d_in[10];
  const float* Wo = (const float*)d_in[11]; const float* bo = (const float*)d_in[12];
  const float* g1 = (const float*)d_in[13]; const float* b1 = (const float*)d_in[14];
  const float* Wi = (const float*)d_in[15]; const float* bi = (const float*)d_in[16];
  const float* Wf = (const float*)d_in[17]; const float* bff = (const float*)d_in[18];
  const float* g2 = (const float*)d_in[19]; const float* b2 = (const float*)d_in[20];
  float* out = (float*)d_out;

  // ---- workspace carving (bytes, 256B-aligned blocks)
  char* base = (char*)d_ws;
  size_t off = 0;
  auto carve = [&](size_t bytes) { void* p = base + off; off += (bytes + 255) & ~255UL; return p; };
  _Float16* h16   = (_Float16*)carve(2048L * 768 * 2);
  _Float16* w4t   = (_Float16*)carve(4L * 768 * 768 * 2);   // WqT,WkT,WvT,WoT
  _Float16* wiT   = (_Float16*)carve(3072L * 768 * 2);
  _Float16* wfT   = (_Float16*)carve(768L * 3072 * 2);
  _Float16* q16   = (_Float16*)carve(2048L * 768 * 2);      // (b,h,s,d)
  _Float16* k16   = (_Float16*)carve(2048L * 768 * 2);      // (b,h,s,d)
  _Float16* v16t  = (_Float16*)carve(2048L * 768 * 2);      // (b,h,d,s)
  _Float16* sc16  = (_Float16*)carve(48L * 512 * 512 * 2);  // scores -> probs
  _Float16* qr16  = (_Float16*)carve(2048L * 768 * 2);
  float*    qbr   = (float*)carve(2048L * 12 * 4);
  _Float16* ctx16 = (_Float16*)carve(2048L * 768 * 2);      // (b,s,h,d)
  float*    t1    = (float*)carve(2048L * 768 * 4);
  float*    attn  = (float*)carve(2048L * 768 * 4);
  _Float16* attn16= (_Float16*)carve(2048L * 768 * 2);
  _Float16* inter16=(_Float16*)carve(2048L * 3072 * 2);
  float*    t2    = (float*)carve(2048L * 768 * 4);

  const dim3 blk(256);
  const long W44 = 768L * 768;

  // ---- operand conversion
  hipLaunchKernelGGL(convT, dim3(24, 24, 4), blk, 0, stream,
    Wq, Wk, Wv, Wo, w4t, w4t + W44, w4t + 2 * W44, w4t + 3 * W44, 768, 768);
  hipLaunchKernelGGL(convT, dim3(96, 24, 1), blk, 0, stream,
    Wi, Wi, Wi, Wi, wiT, wiT, wiT, wiT, 768, 3072);
  hipLaunchKernelGGL(convT, dim3(24, 96, 1), blk, 0, stream,
    Wf, Wf, Wf, Wf, wfT, wfT, wfT, wfT, 3072, 768);
  hipLaunchKernelGGL(conv16, dim3(1536), blk, 0, stream, hidden, h16, 2048L * 768 / 4);

  // ---- QKV fused (z=0,1,2): 128x64 tiles, grid 16x12x3 = 576 blocks
  hipLaunchKernelGGL((gemm16<4, 2, 0>), dim3(16, 12, 3), blk, 0, stream,
    h16, w4t, bq, bk, bv, (const float*)nullptr,
    (float*)nullptr, q16, k16, v16t,
    2048, 768, 768, 768, 768, 768, 0L, W44, 0L, 1.0f);

  hipLaunchKernelGGL(qr_kernel, dim3(2048), blk, 0, stream, q16, Wr, br, qr16, qbr);

  // ---- scores = (q @ k^T)/8 f16, z=(b,h): 128x128, grid 4x4x48
  hipLaunchKernelGGL((gemm16<4, 4, 1>), dim3(4, 4, 48), blk, 0, stream,
    q16, k16, (const float*)nullptr, (const float*)nullptr, (const float*)nullptr,
    (const float*)nullptr, (float*)nullptr, sc16, (_Float16*)nullptr, (_Float16*)nullptr,
    512, 512, 64, 64, 64, 512, 32768L, 32768L, 262144L, 0.125f);

  // ---- + rel term + mask + softmax (in-place f16)
  hipLaunchKernelGGL(relsm2, dim3(2048), blk, 0, stream, rel, graph, qr16, qbr, sc16);

  // ---- ctx = probs @ v : 64x64, grid 8x1x48
  hipLaunchKernelGGL((gemm16<2, 2, 2>), dim3(8, 1, 48), blk, 0, stream,
    sc16, v16t, (const float*)nullptr, (const float*)nullptr, (const float*)nullptr,
    (const float*)nullptr, (float*)nullptr, ctx16, (_Float16*)nullptr, (_Float16*)nullptr,
    512, 64, 512, 512, 512, 768, 262144L, 32768L, 0L, 1.0f);

  // ---- t1 = ctx @ Wo + bo + hidden : 64x64, grid 32x12
  hipLaunchKernelGGL((gemm16<2, 2, 3>), dim3(32, 12, 1), blk, 0, stream,
    ctx16, w4t + 3 * W44, bo, (const float*)nullptr, (const float*)nullptr, hidden,
    t1, (_Float16*)nullptr, (_Float16*)nullptr, (_Float16*)nullptr,
    2048, 768, 768, 768, 768, 768, 0L, 0L, 0L, 1.0f);
  hipLaunchKernelGGL(ln_kernel, dim3(2048), blk, 0, stream, t1, g1, b1, attn, attn16);

  // ---- inter = gelu(attn @ Wi + bi) : 128x128, grid 16x24
  hipLaunchKernelGGL((gemm16<4, 4, 4>), dim3(16, 24, 1), blk, 0, stream,
    attn16, wiT, bi, (const float*)nullptr, (const float*)nullptr, (const float*)nullptr,
    (float*)nullptr, inter16, (_Float16*)nullptr, (_Float16*)nullptr,
    2048, 3072, 768, 768, 768, 3072, 0L, 0L, 0L, 1.0f);

  // ---- t2 = inter @ Wf + bf + attn : 64x64, grid 32x12
  hipLaunchKernelGGL((gemm16<2, 2, 3>), dim3(32, 12, 1), blk, 0, stream,
    inter16, wfT, bff, (const float*)nullptr, (const float*)nullptr, attn,
    t2, (_Float16*)nullptr, (_Float16*)nullptr, (_Float16*)nullptr,
    2048, 768, 3072, 3072, 3072, 768, 0L, 0L, 0L, 1.0f);
  hipLaunchKernelGGL(ln_kernel, dim3(2048), blk, 0, stream, t2, g2, b2, out, (_Float16*)nullptr);
}

// Round 5
// 229.171 us; speedup vs baseline: 5.6284x; 1.1540x over previous
//
#include <hip/hip_runtime.h>
#include <math.h>

typedef float f32x4 __attribute__((ext_vector_type(4)));
typedef _Float16 half8 __attribute__((ext_vector_type(8)));
typedef _Float16 half4 __attribute__((ext_vector_type(4)));

__device__ __forceinline__ void gload16(const void* gsrc, void* ldst) {
  __builtin_amdgcn_global_load_lds(
      (const __attribute__((address_space(1))) void*)gsrc,
      (__attribute__((address_space(3))) void*)ldst, 16, 0, 0);
}

// ---------------------------------------------------------------------------
// f16 MFMA GEMM. A: M x K row-major f16 (lda). B: N x K row-major f16 (ldb).
// BK = 32*KP per barrier phase. LDS layout keeps 64-B rows via KP planes
// ([NB][KP][rows][32]) so global_load_lds's LINEAR lane->LDS mapping (4
// lanes/row) stays valid for every plane (round-3-verified mapping).
// NB=2: double-buffered async prefetch; NB=1: single phase (K == BK).
// XOR bank swizzle on global source col + ds_read col. 4 waves 2x2.
// EPI: 0=QKV(q/k f16 (b,h,s,d); v f16 transposed (b,h,d,s); bias by z)
//      1=f16 out, z-linear (scores)
//      2=PV -> ctx16 (b,s,h,d)
//      4=f16 out + bias + gelu
//      5=f32 partial out at z*sOz (split-K)
// ---------------------------------------------------------------------------
template<int NI, int NJ, int KP, int NB, int EPI>
__global__ __launch_bounds__(256)
void gemm16(const _Float16* __restrict__ Ag, const _Float16* __restrict__ Bg,
            const float* __restrict__ bias0, const float* __restrict__ bias1,
            const float* __restrict__ bias2,
            float* __restrict__ outf, _Float16* __restrict__ oh0,
            _Float16* __restrict__ oh1, _Float16* __restrict__ oh2,
            int M, int N, int K, int lda, int ldb, int ldc,
            long sAz, long sBz, long sOz, float alpha)
{
  constexpr int BM = 32 * NI, BN = 32 * NJ, BK = 32 * KP;
  __shared__ __align__(16) _Float16 As[NB][KP][BM][32];
  __shared__ __align__(16) _Float16 Bs[NB][KP][BN][32];

  const int z = blockIdx.z;
  const _Float16* A = Ag + (long)z * sAz;
  const _Float16* B = Bg + (long)z * sBz;

  const int tid = threadIdx.x, lane = tid & 63, wid = tid >> 6;
  const int m0 = blockIdx.x * BM, n0 = blockIdx.y * BN;
  const int l15 = lane & 15;
  const int wm = (wid >> 1) * (16 * NI), wn = (wid & 1) * (16 * NJ);
  const int lr = lane >> 2;                             // 4 lanes per 64-B row
  const int scol = ((lane & 3) ^ (lane >> 4)) * 8;      // pre-swizzled src col
  const int fcol = ((lane >> 4) ^ (l15 >> 2)) * 8;      // swizzled read col

  f32x4 acc[NI][NJ] = {};

  auto stage = [&](int bf, int kk) {
#pragma unroll
    for (int g = wid; g < BM / 16; g += 4)
#pragma unroll
      for (int kp = 0; kp < KP; ++kp)
        gload16(A + (long)(m0 + g * 16 + lr) * lda + kk + kp * 32 + scol,
                &As[bf][kp][g * 16][0]);
#pragma unroll
    for (int g = wid; g < BN / 16; g += 4)
#pragma unroll
      for (int kp = 0; kp < KP; ++kp)
        gload16(B + (long)(n0 + g * 16 + lr) * ldb + kk + kp * 32 + scol,
                &Bs[bf][kp][g * 16][0]);
  };

  stage(0, 0);
  asm volatile("s_waitcnt vmcnt(0)" ::: "memory");
  __syncthreads();

  int buf = 0;
  for (int k0 = 0; k0 < K; k0 += BK) {
    if (NB == 2 && k0 + BK < K) stage(buf ^ 1, k0 + BK);   // async prefetch
#pragma unroll
    for (int kp = 0; kp < KP; ++kp) {
      half8 af[NI], bfr[NJ];
#pragma unroll
      for (int i = 0; i < NI; ++i)
        af[i] = *reinterpret_cast<const half8*>(&As[buf][kp][wm + i * 16 + l15][fcol]);
#pragma unroll
      for (int j = 0; j < NJ; ++j)
        bfr[j] = *reinterpret_cast<const half8*>(&Bs[buf][kp][wn + j * 16 + l15][fcol]);
#pragma unroll
      for (int i = 0; i < NI; ++i)
#pragma unroll
        for (int j = 0; j < NJ; ++j)
          acc[i][j] = __builtin_amdgcn_mfma_f32_16x16x32_f16(af[i], bfr[j], acc[i][j], 0, 0, 0);
    }
    if (k0 + BK < K) {
      asm volatile("s_waitcnt vmcnt(0)" ::: "memory");  // next tile landed
      __syncthreads();
      buf ^= 1;
    }
  }

#pragma unroll
  for (int i = 0; i < NI; ++i) {
#pragma unroll
    for (int j = 0; j < NJ; ++j) {
      const int row0 = m0 + wm + i * 16 + ((lane >> 4) << 2);
      const int col = n0 + wn + j * 16 + l15;
      if constexpr (EPI == 0) {
        const float* bb = (z == 0) ? bias0 : (z == 1) ? bias1 : bias2;
        const float bv = bb[col];
        const int b = row0 >> 9, h = col >> 6, d = col & 63;
        if (z == 2) {
          half4 pk;
#pragma unroll
          for (int r = 0; r < 4; ++r) pk[r] = (_Float16)(acc[i][j][r] + bv);
          *reinterpret_cast<half4*>(
              &oh2[((long)((b * 12 + h) * 64 + d)) * 512 + (row0 & 511)]) = pk;
        } else {
          _Float16* dst = (z == 0) ? oh0 : oh1;
#pragma unroll
          for (int r = 0; r < 4; ++r)
            dst[((long)((b * 12 + h) * 512 + (row0 & 511) + r)) * 64 + d] =
                (_Float16)(acc[i][j][r] + bv);
        }
      } else {
#pragma unroll
        for (int r = 0; r < 4; ++r) {
          const int row = row0 + r;
          float v = acc[i][j][r] * alpha;
          if constexpr (EPI == 1) {
            oh0[(long)z * sOz + (long)row * ldc + col] = (_Float16)v;
          } else if constexpr (EPI == 2) {
            const int zb = z / 12, zh = z - 12 * zb;
            oh0[((long)(zb * 512 + row)) * 768 + zh * 64 + col] = (_Float16)v;
          } else if constexpr (EPI == 4) {
            v += bias0[col];
            v = 0.5f * v * (1.0f + erff(v * 0.70710678118654752440f));
            oh0[(long)row * ldc + col] = (_Float16)v;
          } else if constexpr (EPI == 5) {
            outf[(long)z * sOz + (long)row * ldc + col] = v;
          }
        }
      }
    }
  }
}

// ---------------------------------------------------------------------------
// Transpose + f32->f16: dst[c][r] = src[r][c]. z picks among up to 4 matrices.
// ---------------------------------------------------------------------------
__global__ __launch_bounds__(256)
void convT(const float* s0, const float* s1, const float* s2, const float* s3,
           _Float16* d0, _Float16* d1, _Float16* d2, _Float16* d3, int R, int C)
{
  const float* src; _Float16* dst;
  switch (blockIdx.z) {
    case 0: src = s0; dst = d0; break;
    case 1: src = s1; dst = d1; break;
    case 2: src = s2; dst = d2; break;
    default: src = s3; dst = d3; break;
  }
  __shared__ float t[32][33];
  const int tid = threadIdx.x, tx = tid & 31, ty = tid >> 5;
  const int c0 = blockIdx.x * 32, r0 = blockIdx.y * 32;
#pragma unroll
  for (int yy = ty; yy < 32; yy += 8)
    t[yy][tx] = src[(long)(r0 + yy) * C + c0 + tx];
  __syncthreads();
#pragma unroll
  for (int yy = ty; yy < 32; yy += 8)
    dst[(long)(c0 + yy) * R + r0 + tx] = (_Float16)t[tx][yy];
}

// flat f32 -> f16
__global__ __launch_bounds__(256)
void conv16(const float* __restrict__ in, _Float16* __restrict__ out, long n4)
{
  const long i = (long)blockIdx.x * 256 + threadIdx.x;
  if (i < n4) {
    const float4 v = reinterpret_cast<const float4*>(in)[i];
    half4 h = {(_Float16)v.x, (_Float16)v.y, (_Float16)v.z, (_Float16)v.w};
    *reinterpret_cast<half4*>(out + i * 4) = h;
  }
}

// ---------------------------------------------------------------------------
// qr16[b,i,h,r] = sum_d q[b,h,i,d] * Wr[r,d];  qbr[b,i,h] = sum_d q*br
// ---------------------------------------------------------------------------
__global__ __launch_bounds__(256)
void qr_kernel(const _Float16* __restrict__ q16, const float* __restrict__ Wr,
               const float* __restrict__ br, _Float16* __restrict__ qr16,
               float* __restrict__ qbr)
{
  __shared__ float qrow[12][64];
  __shared__ float wr[64][65];
  __shared__ float brs[64];
  const long bi = blockIdx.x;
  const int b = (int)(bi >> 9), i = (int)(bi & 511);
  const int tid = threadIdx.x;
  for (int t = tid; t < 768; t += 256) {
    const int h = t >> 6, d = t & 63;
    qrow[h][d] = (float)q16[((long)((b * 12 + h) * 512 + i)) * 64 + d];
  }
  for (int t = tid; t < 4096; t += 256) wr[t >> 6][t & 63] = Wr[t];
  if (tid < 64) brs[tid] = br[tid];
  __syncthreads();
  for (int o = tid; o < 768; o += 256) {
    const int h = o >> 6, r = o & 63;
    float s = 0.f;
#pragma unroll 8
    for (int d = 0; d < 64; ++d) s += qrow[h][d] * wr[r][d];
    qr16[bi * 768 + o] = (_Float16)s;
  }
  if (tid < 12) {
    float s = 0.f;
#pragma unroll 8
    for (int d = 0; d < 64; ++d) s += qrow[tid][d] * brs[d];
    qbr[bi * 12 + tid] = s;
  }
}

// ---------------------------------------------------------------------------
// Per (b,i): s[h][j] = scores16 + qbr/8 + mask; s += (qr . rel)/8 via MFMA
// with rel B-fragments loaded straight from global (consumed exactly once,
// no LDS staging, no barriers in the streaming loop); softmax; probs f16.
// ---------------------------------------------------------------------------
__global__ __launch_bounds__(256)
void relsm2(const float* __restrict__ rel, const float* __restrict__ graph,
            const _Float16* __restrict__ qr16, const float* __restrict__ qbr,
            _Float16* __restrict__ sc)   // in: scores f16, out: probs f16
{
  __shared__ float s[12][512];
  __shared__ float gl[512];
  __shared__ float qb8[12];

  const int bi = blockIdx.x;
  const int b = bi >> 9, i = bi & 511;
  const int tid = threadIdx.x, lane = tid & 63, wid = tid >> 6;
  const int l15 = lane & 15, lk = (lane >> 4) * 8;

  half8 qa0 = {}, qa1 = {};
  if (l15 < 12) {
    qa0 = *reinterpret_cast<const half8*>(qr16 + (long)bi * 768 + l15 * 64 + lk);
    qa1 = *reinterpret_cast<const half8*>(qr16 + (long)bi * 768 + l15 * 64 + 32 + lk);
  }
  if (tid < 12) qb8[tid] = qbr[(long)bi * 12 + tid] * 0.125f;
  for (int t = tid; t < 512; t += 256) gl[t] = graph[(long)bi * 512 + t];
  __syncthreads();
  for (int t = tid; t < 6144; t += 256) {
    const int h = t >> 9, j = t & 511;
    s[h][j] = (float)sc[(((long)(b * 12 + h) * 512) + i) * 512 + j]
            + qb8[h] + (1.0f - gl[j]) * (-1.0e9f);
  }
  __syncthreads();

  const long rbase = ((long)bi * 512 + wid * 16 + l15) * 64 + lk;
  const int jj0 = wid * 16 + l15;
  for (int jt = 0; jt < 512; jt += 64) {
    const float* rp = rel + rbase + (long)jt * 64;
    const float4 v0 = *reinterpret_cast<const float4*>(rp);
    const float4 v1 = *reinterpret_cast<const float4*>(rp + 4);
    const float4 v2 = *reinterpret_cast<const float4*>(rp + 32);
    const float4 v3 = *reinterpret_cast<const float4*>(rp + 36);
    half8 b0, b1;
    b0[0] = (_Float16)v0.x; b0[1] = (_Float16)v0.y; b0[2] = (_Float16)v0.z; b0[3] = (_Float16)v0.w;
    b0[4] = (_Float16)v1.x; b0[5] = (_Float16)v1.y; b0[6] = (_Float16)v1.z; b0[7] = (_Float16)v1.w;
    b1[0] = (_Float16)v2.x; b1[1] = (_Float16)v2.y; b1[2] = (_Float16)v2.z; b1[3] = (_Float16)v2.w;
    b1[4] = (_Float16)v3.x; b1[5] = (_Float16)v3.y; b1[6] = (_Float16)v3.z; b1[7] = (_Float16)v3.w;
    f32x4 acc = {};
    acc = __builtin_amdgcn_mfma_f32_16x16x32_f16(qa0, b0, acc, 0, 0, 0);
    acc = __builtin_amdgcn_mfma_f32_16x16x32_f16(qa1, b1, acc, 0, 0, 0);
#pragma unroll
    for (int r = 0; r < 4; ++r) {
      const int h = ((lane >> 4) << 2) + r;
      if (h < 12) s[h][jt + jj0] += acc[r] * 0.125f;
    }
  }
  __syncthreads();

  for (int h = wid; h < 12; h += 4) {
    float vals[8];
    float mx = -3.4e38f;
#pragma unroll
    for (int t = 0; t < 8; ++t) {
      vals[t] = s[h][lane + (t << 6)];
      mx = fmaxf(mx, vals[t]);
    }
#pragma unroll
    for (int off = 32; off > 0; off >>= 1) mx = fmaxf(mx, __shfl_xor(mx, off, 64));
    float sum = 0.f;
#pragma unroll
    for (int t = 0; t < 8; ++t) { vals[t] = __expf(vals[t] - mx); sum += vals[t]; }
#pragma unroll
    for (int off = 32; off > 0; off >>= 1) sum += __shfl_xor(sum, off, 64);
    const float inv = 1.0f / sum;
    const long base = ((long)((b * 12 + h) * 512 + i)) * 512;
#pragma unroll
    for (int t = 0; t < 8; ++t) sc[base + lane + (t << 6)] = (_Float16)(vals[t] * inv);
  }
}

// ---------------------------------------------------------------------------
// x = p0 + p1 + bias + res (f32, fixed order), then row LayerNorm over 768.
// Optional f16 secondary output.
// ---------------------------------------------------------------------------
__global__ __launch_bounds__(256)
void ln2_kernel(const float* __restrict__ p0, const float* __restrict__ p1,
                const float* __restrict__ bias, const float* __restrict__ res,
                const float* __restrict__ g, const float* __restrict__ bta,
                float* __restrict__ out, _Float16* __restrict__ out16)
{
  __shared__ float red[8];
  const long row = blockIdx.x;
  const int tid = threadIdx.x;
  const long o0i = row * 768 + tid, o1i = o0i + 256, o2i = o0i + 512;
  const float v0 = p0[o0i] + p1[o0i] + bias[tid] + res[o0i];
  const float v1 = p0[o1i] + p1[o1i] + bias[tid + 256] + res[o1i];
  const float v2 = p0[o2i] + p1[o2i] + bias[tid + 512] + res[o2i];
  float sum = v0 + v1 + v2;
#pragma unroll
  for (int off = 32; off > 0; off >>= 1) sum += __shfl_xor(sum, off, 64);
  const int wv = tid >> 6, ln = tid & 63;
  if (ln == 0) red[wv] = sum;
  __syncthreads();
  const float mean = (red[0] + red[1] + red[2] + red[3]) * (1.0f / 768.0f);
  const float d0 = v0 - mean, d1 = v1 - mean, d2 = v2 - mean;
  float sq = d0 * d0 + d1 * d1 + d2 * d2;
#pragma unroll
  for (int off = 32; off > 0; off >>= 1) sq += __shfl_xor(sq, off, 64);
  if (ln == 0) red[4 + wv] = sq;
  __syncthreads();
  const float var = (red[4] + red[5] + red[6] + red[7]) * (1.0f / 768.0f);
  const float rstd = rsqrtf(var + 1e-12f);
  const float o0 = g[tid] * d0 * rstd + bta[tid];
  const float o1 = g[tid + 256] * d1 * rstd + bta[tid + 256];
  const float o2 = g[tid + 512] * d2 * rstd + bta[tid + 512];
  float* orow = out + row * 768;
  orow[tid] = o0; orow[tid + 256] = o1; orow[tid + 512] = o2;
  if (out16) {
    _Float16* hrow = out16 + row * 768;
    hrow[tid] = (_Float16)o0; hrow[tid + 256] = (_Float16)o1; hrow[tid + 512] = (_Float16)o2;
  }
}

// ---------------------------------------------------------------------------
extern "C" void kernel_launch(void* const* d_in, const int* in_sizes, int n_in,
                              void* d_out, int out_size, void* d_ws, size_t ws_size,
                              hipStream_t stream)
{
  const float* hidden = (const float*)d_in[0];
  const float* graph  = (const float*)d_in[1];
  const float* rel    = (const float*)d_in[2];
  const float* Wq = (const float*)d_in[3];  const float* bq = (const float*)d_in[4];
  const float* Wk = (const float*)d_in[5];  const float* bk = (const float*)d_in[6];
  const float* Wv = (const float*)d_in[7];  const float* bv = (const float*)d_in[8];
  const float* Wr = (const float*)d_in[9];  const float* br = (const float*)d_in[10];
  const float* Wo = (const float*)d_in[11]; const float* bo = (const float*)d_in[12];
  const float* g1 = (const float*)d_in[13]; const float* b1 = (const float*)d_in[14];
  const float* Wi = (const float*)d_in[15]; const float* bi = (const float*)d_in[16];
  const float* Wf = (const float*)d_in[17]; const float* bff = (const float*)d_in[18];
  const float* g2 = (const float*)d_in[19]; const float* b2 = (const float*)d_in[20];
  float* out = (float*)d_out;

  // ---- workspace carving (bytes, 256B-aligned blocks)
  char* base = (char*)d_ws;
  size_t off = 0;
  auto carve = [&](size_t bytes) { void* p = base + off; off += (bytes + 255) & ~255UL; return p; };
  _Float16* h16   = (_Float16*)carve(2048L * 768 * 2);
  _Float16* w4t   = (_Float16*)carve(4L * 768 * 768 * 2);   // WqT,WkT,WvT,WoT
  _Float16* wiT   = (_Float16*)carve(3072L * 768 * 2);
  _Float16* wfT   = (_Float16*)carve(768L * 3072 * 2);
  _Float16* q16   = (_Float16*)carve(2048L * 768 * 2);      // (b,h,s,d)
  _Float16* k16   = (_Float16*)carve(2048L * 768 * 2);      // (b,h,s,d)
  _Float16* v16t  = (_Float16*)carve(2048L * 768 * 2);      // (b,h,d,s)
  _Float16* sc16  = (_Float16*)carve(48L * 512 * 512 * 2);  // scores -> probs
  _Float16* qr16  = (_Float16*)carve(2048L * 768 * 2);
  float*    qbr   = (float*)carve(2048L * 12 * 4);
  _Float16* ctx16 = (_Float16*)carve(2048L * 768 * 2);      // (b,s,h,d)
  float*    pk01  = (float*)carve(2L * 2048 * 768 * 4);     // split-K partials
  float*    attn  = (float*)carve(2048L * 768 * 4);
  _Float16* attn16= (_Float16*)carve(2048L * 768 * 2);
  _Float16* inter16=(_Float16*)carve(2048L * 3072 * 2);

  const dim3 blk(256);
  const long W44 = 768L * 768;
  const long PSTR = 2048L * 768;

  // ---- operand conversion
  hipLaunchKernelGGL(convT, dim3(24, 24, 4), blk, 0, stream,
    Wq, Wk, Wv, Wo, w4t, w4t + W44, w4t + 2 * W44, w4t + 3 * W44, 768, 768);
  hipLaunchKernelGGL(convT, dim3(96, 24, 1), blk, 0, stream,
    Wi, Wi, Wi, Wi, wiT, wiT, wiT, wiT, 768, 3072);
  hipLaunchKernelGGL(convT, dim3(24, 96, 1), blk, 0, stream,
    Wf, Wf, Wf, Wf, wfT, wfT, wfT, wfT, 3072, 768);
  hipLaunchKernelGGL(conv16, dim3(1536), blk, 0, stream, hidden, h16, 2048L * 768 / 4);

  // ---- QKV fused (z=0,1,2): 128x64 tiles, BK=64, grid 576
  hipLaunchKernelGGL((gemm16<4, 2, 2, 2, 0>), dim3(16, 12, 3), blk, 0, stream,
    h16, w4t, bq, bk, bv,
    (float*)nullptr, q16, k16, v16t,
    2048, 768, 768, 768, 768, 768, 0L, W44, 0L, 1.0f);

  hipLaunchKernelGGL(qr_kernel, dim3(2048), blk, 0, stream, q16, Wr, br, qr16, qbr);

  // ---- scores = (q @ k^T)/8 f16: 128x128, K=64 single-phase, grid 768
  hipLaunchKernelGGL((gemm16<4, 4, 2, 1, 1>), dim3(4, 4, 48), blk, 0, stream,
    q16, k16, (const float*)nullptr, (const float*)nullptr, (const float*)nullptr,
    (float*)nullptr, sc16, (_Float16*)nullptr, (_Float16*)nullptr,
    512, 512, 64, 64, 64, 512, 32768L, 32768L, 262144L, 0.125f);

  // ---- + rel term + mask + softmax (in-place f16)
  hipLaunchKernelGGL(relsm2, dim3(2048), blk, 0, stream, rel, graph, qr16, qbr, sc16);

  // ---- ctx = probs @ v : 32x64 tiles, BK=64, grid 768
  hipLaunchKernelGGL((gemm16<1, 2, 2, 2, 2>), dim3(16, 1, 48), blk, 0, stream,
    sc16, v16t, (const float*)nullptr, (const float*)nullptr, (const float*)nullptr,
    (float*)nullptr, ctx16, (_Float16*)nullptr, (_Float16*)nullptr,
    512, 64, 512, 512, 512, 768, 262144L, 32768L, 0L, 1.0f);

  // ---- ctx @ Wo split-K (z=2 halves of 768), 64x64, grid 768
  hipLaunchKernelGGL((gemm16<2, 2, 2, 2, 5>), dim3(32, 12, 2), blk, 0, stream,
    ctx16, w4t + 3 * W44, (const float*)nullptr, (const float*)nullptr, (const float*)nullptr,
    pk01, (_Float16*)nullptr, (_Float16*)nullptr, (_Float16*)nullptr,
    2048, 768, 384, 768, 768, 768, 384L, 384L, PSTR, 1.0f);
  hipLaunchKernelGGL(ln2_kernel, dim3(2048), blk, 0, stream,
    pk01, pk01 + PSTR, bo, hidden, g1, b1, attn, attn16);

  // ---- inter = gelu(attn @ Wi + bi) : 128x64, BK=64, grid 768
  hipLaunchKernelGGL((gemm16<4, 2, 2, 2, 4>), dim3(16, 48, 1), blk, 0, stream,
    attn16, wiT, bi, (const float*)nullptr, (const float*)nullptr,
    (float*)nullptr, inter16, (_Float16*)nullptr, (_Float16*)nullptr,
    2048, 3072, 768, 768, 768, 3072, 0L, 0L, 0L, 1.0f);

  // ---- inter @ Wf split-K (z=2 halves of 3072), 64x64, grid 768
  hipLaunchKernelGGL((gemm16<2, 2, 2, 2, 5>), dim3(32, 12, 2), blk, 0, stream,
    inter16, wfT, (const float*)nullptr, (const float*)nullptr, (const float*)nullptr,
    pk01, (_Float16*)nullptr, (_Float16*)nullptr, (_Float16*)nullptr,
    2048, 768, 1536, 3072, 3072, 768, 1536L, 1536L, PSTR, 1.0f);
  hipLaunchKernelGGL(ln2_kernel, dim3(2048), blk, 0, stream,
    pk01, pk01 + PSTR, bff, attn, g2, b2, out, (_Float16*)nullptr);
}

// Round 6
// 219.942 us; speedup vs baseline: 5.8646x; 1.0420x over previous
//
#include <hip/hip_runtime.h>
#include <math.h>

typedef float f32x4 __attribute__((ext_vector_type(4)));
typedef _Float16 half8 __attribute__((ext_vector_type(8)));
typedef _Float16 half4 __attribute__((ext_vector_type(4)));

__device__ __forceinline__ void gload16(const void* gsrc, void* ldst) {
  __builtin_amdgcn_global_load_lds(
      (const __attribute__((address_space(1))) void*)gsrc,
      (__attribute__((address_space(3))) void*)ldst, 16, 0, 0);
}

// ---------------------------------------------------------------------------
// f16 MFMA GEMM. A: M x K row-major f16 (lda). B: N x K row-major f16 (ldb).
// BK = 32*KP per barrier phase. LDS keeps 64-B rows via KP planes
// ([NB][KP][rows][32]) so global_load_lds's LINEAR lane->LDS mapping (4
// lanes/row) stays valid per plane. NB=2: double-buffered async prefetch;
// NB=1: single phase (K == BK). XOR bank swizzle on global source col +
// ds_read col. 4 waves 2x2.
// EPI: 0=QKV(q/k f16 (b,h,s,d); v f16 transposed (b,h,d,s); bias by z)
//      1=f16 out, z-linear (scores)
//      2=PV -> ctx16 (b,s,h,d)
//      4=f16 out + bias + gelu
//      5=f32 partial out at z*sOz (split-K)
// ---------------------------------------------------------------------------
template<int NI, int NJ, int KP, int NB, int EPI>
__global__ __launch_bounds__(256)
void gemm16(const _Float16* __restrict__ Ag, const _Float16* __restrict__ Bg,
            const float* __restrict__ bias0, const float* __restrict__ bias1,
            const float* __restrict__ bias2,
            float* __restrict__ outf, _Float16* __restrict__ oh0,
            _Float16* __restrict__ oh1, _Float16* __restrict__ oh2,
            int M, int N, int K, int lda, int ldb, int ldc,
            long sAz, long sBz, long sOz, float alpha)
{
  constexpr int BM = 32 * NI, BN = 32 * NJ, BK = 32 * KP;
  __shared__ __align__(16) _Float16 As[NB][KP][BM][32];
  __shared__ __align__(16) _Float16 Bs[NB][KP][BN][32];

  const int z = blockIdx.z;
  const _Float16* A = Ag + (long)z * sAz;
  const _Float16* B = Bg + (long)z * sBz;

  const int tid = threadIdx.x, lane = tid & 63, wid = tid >> 6;
  const int m0 = blockIdx.x * BM, n0 = blockIdx.y * BN;
  const int l15 = lane & 15;
  const int wm = (wid >> 1) * (16 * NI), wn = (wid & 1) * (16 * NJ);
  const int lr = lane >> 2;                             // 4 lanes per 64-B row
  const int scol = ((lane & 3) ^ (lane >> 4)) * 8;      // pre-swizzled src col
  const int fcol = ((lane >> 4) ^ (l15 >> 2)) * 8;      // swizzled read col

  f32x4 acc[NI][NJ] = {};

  auto stage = [&](int bf, int kk) {
#pragma unroll
    for (int g = wid; g < BM / 16; g += 4)
#pragma unroll
      for (int kp = 0; kp < KP; ++kp)
        gload16(A + (long)(m0 + g * 16 + lr) * lda + kk + kp * 32 + scol,
                &As[bf][kp][g * 16][0]);
#pragma unroll
    for (int g = wid; g < BN / 16; g += 4)
#pragma unroll
      for (int kp = 0; kp < KP; ++kp)
        gload16(B + (long)(n0 + g * 16 + lr) * ldb + kk + kp * 32 + scol,
                &Bs[bf][kp][g * 16][0]);
  };

  stage(0, 0);
  asm volatile("s_waitcnt vmcnt(0)" ::: "memory");
  __syncthreads();

  int buf = 0;
  for (int k0 = 0; k0 < K; k0 += BK) {
    if (NB == 2 && k0 + BK < K) stage(buf ^ 1, k0 + BK);   // async prefetch
#pragma unroll
    for (int kp = 0; kp < KP; ++kp) {
      half8 af[NI], bfr[NJ];
#pragma unroll
      for (int i = 0; i < NI; ++i)
        af[i] = *reinterpret_cast<const half8*>(&As[buf][kp][wm + i * 16 + l15][fcol]);
#pragma unroll
      for (int j = 0; j < NJ; ++j)
        bfr[j] = *reinterpret_cast<const half8*>(&Bs[buf][kp][wn + j * 16 + l15][fcol]);
#pragma unroll
      for (int i = 0; i < NI; ++i)
#pragma unroll
        for (int j = 0; j < NJ; ++j)
          acc[i][j] = __builtin_amdgcn_mfma_f32_16x16x32_f16(af[i], bfr[j], acc[i][j], 0, 0, 0);
    }
    if (k0 + BK < K) {
      asm volatile("s_waitcnt vmcnt(0)" ::: "memory");  // next tile landed
      __syncthreads();
      buf ^= 1;
    }
  }

#pragma unroll
  for (int i = 0; i < NI; ++i) {
#pragma unroll
    for (int j = 0; j < NJ; ++j) {
      const int row0 = m0 + wm + i * 16 + ((lane >> 4) << 2);
      const int col = n0 + wn + j * 16 + l15;
      if constexpr (EPI == 0) {
        const float* bb = (z == 0) ? bias0 : (z == 1) ? bias1 : bias2;
        const float bv = bb[col];
        const int b = row0 >> 9, h = col >> 6, d = col & 63;
        if (z == 2) {
          half4 pk;
#pragma unroll
          for (int r = 0; r < 4; ++r) pk[r] = (_Float16)(acc[i][j][r] + bv);
          *reinterpret_cast<half4*>(
              &oh2[((long)((b * 12 + h) * 64 + d)) * 512 + (row0 & 511)]) = pk;
        } else {
          _Float16* dst = (z == 0) ? oh0 : oh1;
#pragma unroll
          for (int r = 0; r < 4; ++r)
            dst[((long)((b * 12 + h) * 512 + (row0 & 511) + r)) * 64 + d] =
                (_Float16)(acc[i][j][r] + bv);
        }
      } else {
#pragma unroll
        for (int r = 0; r < 4; ++r) {
          const int row = row0 + r;
          float v = acc[i][j][r] * alpha;
          if constexpr (EPI == 1) {
            oh0[(long)z * sOz + (long)row * ldc + col] = (_Float16)v;
          } else if constexpr (EPI == 2) {
            const int zb = z / 12, zh = z - 12 * zb;
            oh0[((long)(zb * 512 + row)) * 768 + zh * 64 + col] = (_Float16)v;
          } else if constexpr (EPI == 4) {
            v += bias0[col];
            v = 0.5f * v * (1.0f + erff(v * 0.70710678118654752440f));
            oh0[(long)row * ldc + col] = (_Float16)v;
          } else if constexpr (EPI == 5) {
            outf[(long)z * sOz + (long)row * ldc + col] = v;
          }
        }
      }
    }
  }
}

// ---------------------------------------------------------------------------
// Fused prep: all weight transposes (f32->f16) + hidden f32->f16, one launch.
// Block ranges: [0,2304) WqT/WkT/WvT/WoT (4 x 576 tiles of 24x24);
// [2304,4608) WiT (96x24); [4608,6912) WfT (24x96); [6912,8448) h16 flat.
// ---------------------------------------------------------------------------
__global__ __launch_bounds__(256)
void prep_kernel(const float* __restrict__ Wq, const float* __restrict__ Wk,
                 const float* __restrict__ Wv, const float* __restrict__ Wo,
                 const float* __restrict__ Wi, const float* __restrict__ Wf,
                 const float* __restrict__ hidden,
                 _Float16* __restrict__ w4t, _Float16* __restrict__ wiT,
                 _Float16* __restrict__ wfT, _Float16* __restrict__ h16)
{
  const int id = blockIdx.x, tid = threadIdx.x;
  if (id >= 6912) {  // flat f32 -> f16 on hidden
    const long i = (long)(id - 6912) * 256 + tid;
    const float4 v = reinterpret_cast<const float4*>(hidden)[i];
    half4 h = {(_Float16)v.x, (_Float16)v.y, (_Float16)v.z, (_Float16)v.w};
    *reinterpret_cast<half4*>(h16 + i * 4) = h;
    return;
  }
  const float* src; _Float16* dst; int R, C, cx, ry;
  if (id < 2304) {
    const int m = id / 576, t = id - m * 576;
    const float* ss[4] = {Wq, Wk, Wv, Wo};
    src = ss[m]; dst = w4t + (long)m * 768 * 768;
    R = 768; C = 768; cx = t % 24; ry = t / 24;
  } else if (id < 4608) {
    const int t = id - 2304;
    src = Wi; dst = wiT; R = 768; C = 3072; cx = t % 96; ry = t / 96;
  } else {
    const int t = id - 4608;
    src = Wf; dst = wfT; R = 3072; C = 768; cx = t % 24; ry = t / 24;
  }
  __shared__ float tbuf[32][33];
  const int tx = tid & 31, ty = tid >> 5;
  const int c0 = cx * 32, r0 = ry * 32;
#pragma unroll
  for (int yy = ty; yy < 32; yy += 8)
    tbuf[yy][tx] = src[(long)(r0 + yy) * C + c0 + tx];
  __syncthreads();
#pragma unroll
  for (int yy = ty; yy < 32; yy += 8)
    dst[(long)(c0 + yy) * R + r0 + tx] = (_Float16)tbuf[tx][yy];
}

// ---------------------------------------------------------------------------
// Per (b,i), fused: qr[h,r] = sum_d q[b,h,i,d]*Wr[r,d] (in-block);
// s[h][j] = scores16 + (qr.br)/8 + mask; s += (qr . rel)/8 via MFMA with rel
// B-fragments straight from global (streamed once, no barriers in the loop);
// softmax over j; probs f16 in-place. Wr/qrow staging overlays s[].
// ---------------------------------------------------------------------------
__global__ __launch_bounds__(256)
void relsm3(const float* __restrict__ rel, const float* __restrict__ graph,
            const _Float16* __restrict__ q16, const float* __restrict__ Wr,
            const float* __restrict__ br,
            _Float16* __restrict__ sc)   // in: scores f16, out: probs f16
{
  __shared__ float s[12][512];           // phase 0/1 overlay: wr[64][65]+qrow
  __shared__ float qrl[12][64];
  __shared__ float gl[512];
  __shared__ float qb8[12];

  float* wrbuf = &s[0][0];               // [64][65] = 4160 floats
  float* qrowbuf = wrbuf + 64 * 65;      // [12][64] = 768 floats (<= 6144 tot)

  const int bi = blockIdx.x;
  const int b = bi >> 9, i = bi & 511;
  const int tid = threadIdx.x, lane = tid & 63, wid = tid >> 6;
  const int l15 = lane & 15, lk = (lane >> 4) * 8;

  // P0: stage Wr, q-row, graph
  for (int t = tid; t < 4096; t += 256) wrbuf[(t >> 6) * 65 + (t & 63)] = Wr[t];
  for (int t = tid; t < 768; t += 256) {
    const int h = t >> 6, d = t & 63;
    qrowbuf[h * 64 + d] = (float)q16[((long)((b * 12 + h) * 512 + i)) * 64 + d];
  }
  for (int t = tid; t < 512; t += 256) gl[t] = graph[(long)bi * 512 + t];
  __syncthreads();

  // P1: qr + qbr
  for (int o = tid; o < 768; o += 256) {
    const int h = o >> 6, r = o & 63;
    float ssum = 0.f;
#pragma unroll 8
    for (int d = 0; d < 64; ++d) ssum += qrowbuf[h * 64 + d] * wrbuf[r * 65 + d];
    qrl[h][r] = ssum;
  }
  if (tid < 12) {
    float ssum = 0.f;
#pragma unroll 8
    for (int d = 0; d < 64; ++d) ssum += qrowbuf[tid * 64 + d] * br[d];
    qb8[tid] = ssum * 0.125f;
  }
  __syncthreads();

  // P2: qa fragments + s init (overwrites wr/qrow overlay)
  half8 qa0 = {}, qa1 = {};
  if (l15 < 12) {
#pragma unroll
    for (int e = 0; e < 8; ++e) {
      qa0[e] = (_Float16)qrl[l15][lk + e];
      qa1[e] = (_Float16)qrl[l15][32 + lk + e];
    }
  }
  for (int t = tid; t < 6144; t += 256) {
    const int h = t >> 9, j = t & 511;
    s[h][j] = (float)sc[(((long)(b * 12 + h) * 512) + i) * 512 + j]
            + qb8[h] + (1.0f - gl[j]) * (-1.0e9f);
  }
  __syncthreads();

  // P3: stream rel once, MFMA rel-dot, RMW s (no barriers inside)
  const long rbase = ((long)bi * 512 + wid * 16 + l15) * 64 + lk;
  const int jj0 = wid * 16 + l15;
  for (int jt = 0; jt < 512; jt += 64) {
    const float* rp = rel + rbase + (long)jt * 64;
    const float4 v0 = *reinterpret_cast<const float4*>(rp);
    const float4 v1 = *reinterpret_cast<const float4*>(rp + 4);
    const float4 v2 = *reinterpret_cast<const float4*>(rp + 32);
    const float4 v3 = *reinterpret_cast<const float4*>(rp + 36);
    half8 b0, b1;
    b0[0] = (_Float16)v0.x; b0[1] = (_Float16)v0.y; b0[2] = (_Float16)v0.z; b0[3] = (_Float16)v0.w;
    b0[4] = (_Float16)v1.x; b0[5] = (_Float16)v1.y; b0[6] = (_Float16)v1.z; b0[7] = (_Float16)v1.w;
    b1[0] = (_Float16)v2.x; b1[1] = (_Float16)v2.y; b1[2] = (_Float16)v2.z; b1[3] = (_Float16)v2.w;
    b1[4] = (_Float16)v3.x; b1[5] = (_Float16)v3.y; b1[6] = (_Float16)v3.z; b1[7] = (_Float16)v3.w;
    f32x4 acc = {};
    acc = __builtin_amdgcn_mfma_f32_16x16x32_f16(qa0, b0, acc, 0, 0, 0);
    acc = __builtin_amdgcn_mfma_f32_16x16x32_f16(qa1, b1, acc, 0, 0, 0);
#pragma unroll
    for (int r = 0; r < 4; ++r) {
      const int h = ((lane >> 4) << 2) + r;
      if (h < 12) s[h][jt + jj0] += acc[r] * 0.125f;
    }
  }
  __syncthreads();

  // P4: softmax + write probs f16
  for (int h = wid; h < 12; h += 4) {
    float vals[8];
    float mx = -3.4e38f;
#pragma unroll
    for (int t = 0; t < 8; ++t) {
      vals[t] = s[h][lane + (t << 6)];
      mx = fmaxf(mx, vals[t]);
    }
#pragma unroll
    for (int off = 32; off > 0; off >>= 1) mx = fmaxf(mx, __shfl_xor(mx, off, 64));
    float sum = 0.f;
#pragma unroll
    for (int t = 0; t < 8; ++t) { vals[t] = __expf(vals[t] - mx); sum += vals[t]; }
#pragma unroll
    for (int off = 32; off > 0; off >>= 1) sum += __shfl_xor(sum, off, 64);
    const float inv = 1.0f / sum;
    const long base = (((long)(b * 12 + h) * 512) + i) * 512;
#pragma unroll
    for (int t = 0; t < 8; ++t) sc[base + lane + (t << 6)] = (_Float16)(vals[t] * inv);
  }
}

// ---------------------------------------------------------------------------
// x = p0 + p1 + bias + res (f32, fixed order), then row LayerNorm over 768.
// Optional f16 secondary output.
// ---------------------------------------------------------------------------
__global__ __launch_bounds__(256)
void ln2_kernel(const float* __restrict__ p0, const float* __restrict__ p1,
                const float* __restrict__ bias, const float* __restrict__ res,
                const float* __restrict__ g, const float* __restrict__ bta,
                float* __restrict__ out, _Float16* __restrict__ out16)
{
  __shared__ float red[8];
  const long row = blockIdx.x;
  const int tid = threadIdx.x;
  const long o0i = row * 768 + tid, o1i = o0i + 256, o2i = o0i + 512;
  const float v0 = p0[o0i] + p1[o0i] + bias[tid] + res[o0i];
  const float v1 = p0[o1i] + p1[o1i] + bias[tid + 256] + res[o1i];
  const float v2 = p0[o2i] + p1[o2i] + bias[tid + 512] + res[o2i];
  float sum = v0 + v1 + v2;
#pragma unroll
  for (int off = 32; off > 0; off >>= 1) sum += __shfl_xor(sum, off, 64);
  const int wv = tid >> 6, ln = tid & 63;
  if (ln == 0) red[wv] = sum;
  __syncthreads();
  const float mean = (red[0] + red[1] + red[2] + red[3]) * (1.0f / 768.0f);
  const float d0 = v0 - mean, d1 = v1 - mean, d2 = v2 - mean;
  float sq = d0 * d0 + d1 * d1 + d2 * d2;
#pragma unroll
  for (int off = 32; off > 0; off >>= 1) sq += __shfl_xor(sq, off, 64);
  if (ln == 0) red[4 + wv] = sq;
  __syncthreads();
  const float var = (red[4] + red[5] + red[6] + red[7]) * (1.0f / 768.0f);
  const float rstd = rsqrtf(var + 1e-12f);
  const float o0 = g[tid] * d0 * rstd + bta[tid];
  const float o1 = g[tid + 256] * d1 * rstd + bta[tid + 256];
  const float o2 = g[tid + 512] * d2 * rstd + bta[tid + 512];
  float* orow = out + row * 768;
  orow[tid] = o0; orow[tid + 256] = o1; orow[tid + 512] = o2;
  if (out16) {
    _Float16* hrow = out16 + row * 768;
    hrow[tid] = (_Float16)o0; hrow[tid + 256] = (_Float16)o1; hrow[tid + 512] = (_Float16)o2;
  }
}

// ---------------------------------------------------------------------------
extern "C" void kernel_launch(void* const* d_in, const int* in_sizes, int n_in,
                              void* d_out, int out_size, void* d_ws, size_t ws_size,
                              hipStream_t stream)
{
  const float* hidden = (const float*)d_in[0];
  const float* graph  = (const float*)d_in[1];
  const float* rel    = (const float*)d_in[2];
  const float* Wq = (const float*)d_in[3];  const float* bq = (const float*)d_in[4];
  const float* Wk = (const float*)d_in[5];  const float* bk = (const float*)d_in[6];
  const float* Wv = (const float*)d_in[7];  const float* bv = (const float*)d_in[8];
  const float* Wr = (const float*)d_in[9];  const float* br = (const float*)d_in[10];
  const float* Wo = (const float*)d_in[11]; const float* bo = (const float*)d_in[12];
  const float* g1 = (const float*)d_in[13]; const float* b1 = (const float*)d_in[14];
  const float* Wi = (const float*)d_in[15]; const float* bi = (const float*)d_in[16];
  const float* Wf = (const float*)d_in[17]; const float* bff = (const float*)d_in[18];
  const float* g2 = (const float*)d_in[19]; const float* b2 = (const float*)d_in[20];
  float* out = (float*)d_out;

  // ---- workspace carving (bytes, 256B-aligned blocks)
  char* base = (char*)d_ws;
  size_t off = 0;
  auto carve = [&](size_t bytes) { void* p = base + off; off += (bytes + 255) & ~255UL; return p; };
  _Float16* h16   = (_Float16*)carve(2048L * 768 * 2);
  _Float16* w4t   = (_Float16*)carve(4L * 768 * 768 * 2);   // WqT,WkT,WvT,WoT
  _Float16* wiT   = (_Float16*)carve(3072L * 768 * 2);
  _Float16* wfT   = (_Float16*)carve(768L * 3072 * 2);
  _Float16* q16   = (_Float16*)carve(2048L * 768 * 2);      // (b,h,s,d)
  _Float16* k16   = (_Float16*)carve(2048L * 768 * 2);      // (b,h,s,d)
  _Float16* v16t  = (_Float16*)carve(2048L * 768 * 2);      // (b,h,d,s)
  _Float16* sc16  = (_Float16*)carve(48L * 512 * 512 * 2);  // scores -> probs
  _Float16* ctx16 = (_Float16*)carve(2048L * 768 * 2);      // (b,s,h,d)
  float*    pk01  = (float*)carve(2L * 2048 * 768 * 4);     // split-K partials
  float*    attn  = (float*)carve(2048L * 768 * 4);
  _Float16* attn16= (_Float16*)carve(2048L * 768 * 2);
  _Float16* inter16=(_Float16*)carve(2048L * 3072 * 2);

  const dim3 blk(256);
  const long W44 = 768L * 768;
  const long PSTR = 2048L * 768;

  // ---- fused operand conversion (one launch)
  hipLaunchKernelGGL(prep_kernel, dim3(8448), blk, 0, stream,
    Wq, Wk, Wv, Wo, Wi, Wf, hidden, w4t, wiT, wfT, h16);

  // ---- QKV fused (z=0,1,2): 128x64 tiles, BK=64, grid 576
  hipLaunchKernelGGL((gemm16<4, 2, 2, 2, 0>), dim3(16, 12, 3), blk, 0, stream,
    h16, w4t, bq, bk, bv,
    (float*)nullptr, q16, k16, v16t,
    2048, 768, 768, 768, 768, 768, 0L, W44, 0L, 1.0f);

  // ---- scores = (q @ k^T)/8 f16: 128x128, K=64 single-phase, grid 768
  hipLaunchKernelGGL((gemm16<4, 4, 2, 1, 1>), dim3(4, 4, 48), blk, 0, stream,
    q16, k16, (const float*)nullptr, (const float*)nullptr, (const float*)nullptr,
    (float*)nullptr, sc16, (_Float16*)nullptr, (_Float16*)nullptr,
    512, 512, 64, 64, 64, 512, 32768L, 32768L, 262144L, 0.125f);

  // ---- qr (in-block) + rel term + mask + softmax (in-place f16)
  hipLaunchKernelGGL(relsm3, dim3(2048), blk, 0, stream,
    rel, graph, q16, Wr, br, sc16);

  // ---- ctx = probs @ v : 32x64 tiles, BK=64, grid 768
  hipLaunchKernelGGL((gemm16<1, 2, 2, 2, 2>), dim3(16, 1, 48), blk, 0, stream,
    sc16, v16t, (const float*)nullptr, (const float*)nullptr, (const float*)nullptr,
    (float*)nullptr, ctx16, (_Float16*)nullptr, (_Float16*)nullptr,
    512, 64, 512, 512, 512, 768, 262144L, 32768L, 0L, 1.0f);

  // ---- ctx @ Wo split-K (z=2 halves of 768), 64x64, grid 768
  hipLaunchKernelGGL((gemm16<2, 2, 2, 2, 5>), dim3(32, 12, 2), blk, 0, stream,
    ctx16, w4t + 3 * W44, (const float*)nullptr, (const float*)nullptr, (const float*)nullptr,
    pk01, (_Float16*)nullptr, (_Float16*)nullptr, (_Float16*)nullptr,
    2048, 768, 384, 768, 768, 768, 384L, 384L, PSTR, 1.0f);
  hipLaunchKernelGGL(ln2_kernel, dim3(2048), blk, 0, stream,
    pk01, pk01 + PSTR, bo, hidden, g1, b1, attn, attn16);

  // ---- inter = gelu(attn @ Wi + bi) : 128x64, BK=64, grid 768
  hipLaunchKernelGGL((gemm16<4, 2, 2, 2, 4>), dim3(16, 48, 1), blk, 0, stream,
    attn16, wiT, bi, (const float*)nullptr, (const float*)nullptr,
    (float*)nullptr, inter16, (_Float16*)nullptr, (_Float16*)nullptr,
    2048, 3072, 768, 768, 768, 3072, 0L, 0L, 0L, 1.0f);

  // ---- inter @ Wf split-K (z=2 halves of 3072), 64x64, grid 768
  hipLaunchKernelGGL((gemm16<2, 2, 2, 2, 5>), dim3(32, 12, 2), blk, 0, stream,
    inter16, wfT, (const float*)nullptr, (const float*)nullptr, (const float*)nullptr,
    pk01, (_Float16*)nullptr, (_Float16*)nullptr, (_Float16*)nullptr,
    2048, 768, 1536, 3072, 3072, 768, 1536L, 1536L, PSTR, 1.0f);
  hipLaunchKernelGGL(ln2_kernel, dim3(2048), blk, 0, stream,
    pk01, pk01 + PSTR, bff, attn, g2, b2, out, (_Float16*)nullptr);
}